// Round 1
// baseline (6263.193 us; speedup 1.0000x reference)
//
#include <hip/hip_runtime.h>
#include <hip/hip_bf16.h>
#include <math.h>

#define D_    512
#define NHH   8
#define DH_   64
#define T_    16
#define T1_   17
#define HWL   256
#define B__   2
#define NEGV  -1e9f

__device__ inline float wave_sum(float v){
  #pragma unroll
  for(int o=32;o>0;o>>=1) v += __shfl_xor(v,o,64);
  return v;
}

// ---------------- embedding + LN  (rows = B*T1*HW, one wave per row) ----------------
__global__ __launch_bounds__(256) void embed_ln_kernel(
    const int* __restrict__ codes, const float* __restrict__ emb,
    const float* __restrict__ cls, const float* __restrict__ hpos,
    const float* __restrict__ wpos, const float* __restrict__ g,
    const float* __restrict__ bta, float* __restrict__ X){
  int row  = blockIdx.x*4 + (threadIdx.x>>6);
  int lane = threadIdx.x & 63;
  int hw = row % HWL; int bt = row / HWL; int t = bt % T1_; int bb = bt / T1_;
  float v[8];
  if(t < T_){
    int code = codes[(bb*T_ + t)*HWL + hw];
    const float* ep = emb  + (size_t)code*D_;
    const float* hp = hpos + (size_t)(hw & 15)*D_;
    const float* wp = wpos + (size_t)(hw >> 4)*D_;
    #pragma unroll
    for(int j=0;j<8;j++){ int d = lane + j*64; v[j] = ep[d] + hp[d] + wp[d]; }
  } else {
    #pragma unroll
    for(int j=0;j<8;j++) v[j] = cls[lane + j*64];
  }
  float s=0;
  #pragma unroll
  for(int j=0;j<8;j++) s += v[j];
  s = wave_sum(s);
  float mean = s*(1.f/512.f);
  float s2=0;
  #pragma unroll
  for(int j=0;j<8;j++){ float d0=v[j]-mean; s2 += d0*d0; }
  s2 = wave_sum(s2);
  float inv = rsqrtf(s2*(1.f/512.f) + 1e-5f);
  float* o = X + (size_t)row*D_;
  #pragma unroll
  for(int j=0;j<8;j++){ int d = lane + j*64; o[d] = (v[j]-mean)*inv*g[d] + bta[d]; }
}

// ---------------- generic row LayerNorm with batch-row remap ----------------
__global__ __launch_bounds__(256) void ln_kernel(
    const float* __restrict__ in, float* __restrict__ out,
    const float* __restrict__ g, const float* __restrict__ bta,
    int c_rpb, int s_rpb){
  int row  = blockIdx.x*4 + (threadIdx.x>>6);
  int lane = threadIdx.x & 63;
  int bb = row / c_rpb; int rem = row - bb*c_rpb;
  const float* p = in + ((size_t)bb*s_rpb + rem)*D_;
  float v[8]; float s=0;
  #pragma unroll
  for(int j=0;j<8;j++){ v[j] = p[lane + j*64]; s += v[j]; }
  s = wave_sum(s);
  float mean = s*(1.f/512.f);
  float s2=0;
  #pragma unroll
  for(int j=0;j<8;j++){ float d0=v[j]-mean; s2 += d0*d0; }
  s2 = wave_sum(s2);
  float inv = rsqrtf(s2*(1.f/512.f) + 1e-5f);
  float* o = out + (size_t)row*D_;
  #pragma unroll
  for(int j=0;j<8;j++){ int d = lane + j*64; o[d] = (v[j]-mean)*inv*g[d] + bta[d]; }
}

// ---------------- fp32 tiled GEMM: out = act(A@W + bias) [+ resid], 64x64 tile ----------------
template<int ACT, bool RES>
__global__ __launch_bounds__(256) void gemm_kernel(
    const float* __restrict__ A, const float* __restrict__ W,
    const float* __restrict__ bias, float* __restrict__ out,
    const float* __restrict__ resid, int K, int N, int c_rpb, int o_rpb){
  __shared__ float As[32][68];   // transposed: As[k][m]
  __shared__ float Bs[32][68];   // Bs[k][n]
  int tid = threadIdx.x;
  int ty = tid >> 4, tx = tid & 15;
  int row0 = blockIdx.y << 6, col0 = blockIdx.x << 6;
  float acc[4][4] = {};
  for(int k0=0;k0<K;k0+=32){
    #pragma unroll
    for(int it=0;it<2;++it){
      int f = tid + (it<<8);
      int rm = f >> 3, kc = (f & 7) << 2;
      const float4 av = *reinterpret_cast<const float4*>(&A[(size_t)(row0+rm)*K + k0 + kc]);
      As[kc+0][rm]=av.x; As[kc+1][rm]=av.y; As[kc+2][rm]=av.z; As[kc+3][rm]=av.w;
      int kr = f >> 4, cn = (f & 15) << 2;
      *reinterpret_cast<float4*>(&Bs[kr][cn]) =
        *reinterpret_cast<const float4*>(&W[(size_t)(k0+kr)*N + col0 + cn]);
    }
    __syncthreads();
    #pragma unroll
    for(int kk=0;kk<32;kk++){
      float4 a = *reinterpret_cast<const float4*>(&As[kk][ty<<2]);
      float4 b = *reinterpret_cast<const float4*>(&Bs[kk][tx<<2]);
      acc[0][0] += a.x*b.x; acc[0][1] += a.x*b.y; acc[0][2] += a.x*b.z; acc[0][3] += a.x*b.w;
      acc[1][0] += a.y*b.x; acc[1][1] += a.y*b.y; acc[1][2] += a.y*b.z; acc[1][3] += a.y*b.w;
      acc[2][0] += a.z*b.x; acc[2][1] += a.z*b.y; acc[2][2] += a.z*b.z; acc[2][3] += a.z*b.w;
      acc[3][0] += a.w*b.x; acc[3][1] += a.w*b.y; acc[3][2] += a.w*b.z; acc[3][3] += a.w*b.w;
    }
    __syncthreads();
  }
  #pragma unroll
  for(int i=0;i<4;i++){
    int r = row0 + (ty<<2) + i;
    int bb = r / c_rpb;
    size_t orow = (size_t)bb*o_rpb + (r - bb*c_rpb);
    #pragma unroll
    for(int j=0;j<4;j++){
      int c = col0 + (tx<<2) + j;
      float val = acc[i][j] + bias[c];
      if(ACT==1) val = tanhf(val);
      if(RES) val += resid[orow*(size_t)N + c];
      out[orow*(size_t)N + c] = val;
    }
  }
}

// ---------------- spatial 3x3 windowed attention (wave per (loc,head)) ----------------
__global__ __launch_bounds__(512) void spatial_attn_kernel(
    const float* __restrict__ Q, const float* __restrict__ K,
    const float* __restrict__ V, float* __restrict__ O){
  int loc = blockIdx.x;                 // (b*T + t)*HW + hw, compact
  int hw = loc & 255;
  int hh = hw >> 4, ww = hw & 15;
  int head = threadIdx.x >> 6, dh = threadIdx.x & 63;
  size_t cbase = (size_t)loc*D_ + head*DH_ + dh;
  float q = Q[cbase];
  float lg[9];
  int nrow[9];
  #pragma unroll
  for(int s=0;s<9;s++){
    int a = s/3 - 1, b2 = s%3 - 1;
    int nh = hh + a, nw = ww + b2;
    bool ok = ((unsigned)nh < 16u) && ((unsigned)nw < 16u);
    nrow[s] = ok ? (loc - hw + (nh<<4) + nw) : -1;
    float partial = ok ? q * K[(size_t)nrow[s]*D_ + head*DH_ + dh] : 0.f;
    float dot = wave_sum(partial);
    lg[s] = ok ? dot*0.125f : NEGV;
  }
  float m = lg[0];
  #pragma unroll
  for(int s=1;s<9;s++) m = fmaxf(m, lg[s]);
  float den = 0.f, wv[9];
  #pragma unroll
  for(int s=0;s<9;s++){ wv[s] = __expf(lg[s]-m); den += wv[s]; }
  float inv = 1.f/den;
  float acc = 0.f;
  #pragma unroll
  for(int s=0;s<9;s++){
    if(nrow[s] >= 0) acc += wv[s] * V[(size_t)nrow[s]*D_ + head*DH_ + dh];
  }
  O[cbase] = acc*inv;
}

// ---------------- RoPE (in place), rows = B*T1*HW, 256 pairs/row ----------------
__global__ __launch_bounds__(256) void rope_kernel(float* __restrict__ X){
  int gid = blockIdx.x*256 + threadIdx.x;
  int pair = gid & 255; int row = gid >> 8;
  int t = (row >> 8) % T1_;             // row = (bb*T1+t)*256 + hw
  int h = pair >> 5, i = pair & 31;
  float* p = X + (size_t)row*D_ + h*DH_;
  float x1 = p[i], x2 = p[i+32];
  float freq = __expf(-9.210340372f * (float)i * (1.f/32.f)); // 10000^{-i/32}
  float ang = (float)t * freq;
  float c = cosf(ang), sn = sinf(ang);
  p[i]    = x1*c - x2*sn;
  p[i+32] = x2*c + x1*sn;
}

// ---------------- export roped K / V (frames 0..15) to outputs ----------------
__global__ __launch_bounds__(256) void export_kv_kernel(
    const float* __restrict__ KT, const float* __restrict__ VT,
    float* __restrict__ kout, float* __restrict__ vout){
  int gid = blockIdx.x*256 + threadIdx.x;   // (((b*HW+hw)*NH+h)*16+t)*64+dh
  int dh = gid & 63; int r = gid >> 6;
  int t = r & 15; r >>= 4; int h = r & 7; r >>= 3; int hw = r & 255; int bb = r >> 8;
  size_t src = ((size_t)(bb*T1_ + t)*HWL + hw)*D_ + h*DH_ + dh;
  kout[gid] = KT[src];
  vout[gid] = VT[src];
}

// ---------------- temporal masked logits (wave per (b,hw,h,t), lane = key) ----------------
__global__ __launch_bounds__(256) void temporal_logits_kernel(
    const float* __restrict__ QT, const float* __restrict__ KT, float* __restrict__ LT){
  int wid  = (blockIdx.x << 2) + (threadIdx.x >> 6);
  int lane = threadIdx.x & 63;
  int t = wid % T1_; int r = wid / T1_;
  int h = r & 7; r >>= 3; int hw = r & 255; int bb = r >> 8;
  if(lane >= T1_) return;
  int u = lane;
  const float* qp = QT + ((size_t)(bb*T1_ + t)*HWL + hw)*D_ + h*DH_;
  const float* kp = KT + ((size_t)(bb*T1_ + u)*HWL + hw)*D_ + h*DH_;
  float dot = 0.f;
  #pragma unroll
  for(int d=0; d<DH_; d++) dot += qp[d]*kp[d];
  bool masked = (u > t) || (t == T_ && u == T_);
  LT[((((size_t)bb*HWL + hw)*NHH + h)*T1_ + t)*T1_ + u] = masked ? NEGV : dot*0.125f;
}

// ---------------- temporal softmax + A@V (wave per (b,hw,h,t), lane = dh) ----------------
__global__ __launch_bounds__(256) void temporal_av_kernel(
    const float* __restrict__ LT, const float* __restrict__ VT, float* __restrict__ OT){
  int wid  = (blockIdx.x << 2) + (threadIdx.x >> 6);
  int lane = threadIdx.x & 63;
  int t = wid % T1_; int r = wid / T1_;
  int h = r & 7; r >>= 3; int hw = r & 255; int bb = r >> 8;
  const float* lp = LT + ((((size_t)bb*HWL + hw)*NHH + h)*T1_ + t)*T1_;
  float lg[T1_];
  float m = -1e30f;
  #pragma unroll
  for(int u=0;u<T1_;u++){ lg[u] = lp[u]; m = fmaxf(m, lg[u]); }
  float den = 0.f;
  #pragma unroll
  for(int u=0;u<T1_;u++){ lg[u] = __expf(lg[u]-m); den += lg[u]; }
  float inv = 1.f/den;
  float acc = 0.f;
  #pragma unroll
  for(int u=0;u<T1_;u++){
    acc += lg[u] * VT[((size_t)(bb*T1_ + u)*HWL + hw)*D_ + h*DH_ + lane];
  }
  OT[((size_t)(bb*T1_ + t)*HWL + hw)*D_ + h*DH_ + lane] = acc*inv;
}

// ---------------- frame-0 spatial mean broadcast ----------------
__global__ __launch_bounds__(256) void avg_frame0_kernel(float* __restrict__ X){
  int d = blockIdx.x & 511; int bb = blockIdx.x >> 9;
  int hw = threadIdx.x;
  __shared__ float sm[256];
  size_t idx = ((size_t)(bb*T1_)*HWL + hw)*D_ + d;
  sm[hw] = X[idx];
  __syncthreads();
  for(int o=128;o>0;o>>=1){ if(hw<o) sm[hw] += sm[hw+o]; __syncthreads(); }
  X[idx] = sm[0]*(1.f/256.f);
}

extern "C" void kernel_launch(void* const* d_in, const int* in_sizes, int n_in,
                              void* d_out, int out_size, void* d_ws, size_t ws_size,
                              hipStream_t stream){
  const int*   codes = (const int*)  d_in[0];
  const float* emb   = (const float*)d_in[1];
  const float* cls   = (const float*)d_in[2];
  const float* hpos  = (const float*)d_in[3];
  const float* wpos  = (const float*)d_in[4];
  const float* eng   = (const float*)d_in[5];
  const float* enb   = (const float*)d_in[6];
  const float* sn_g  = (const float*)d_in[7];
  const float* sn_b  = (const float*)d_in[8];
  const float* s_wq  = (const float*)d_in[9];
  const float* s_bq  = (const float*)d_in[10];
  const float* s_wk  = (const float*)d_in[11];
  const float* s_bk  = (const float*)d_in[12];
  const float* s_wv  = (const float*)d_in[13];
  const float* s_bv  = (const float*)d_in[14];
  const float* s_wo  = (const float*)d_in[15];
  const float* s_bo  = (const float*)d_in[16];
  const float* tn_g  = (const float*)d_in[17];
  const float* tn_b  = (const float*)d_in[18];
  const float* t_wq  = (const float*)d_in[19];
  const float* t_bq  = (const float*)d_in[20];
  const float* t_wk  = (const float*)d_in[21];
  const float* t_bk  = (const float*)d_in[22];
  const float* t_wv  = (const float*)d_in[23];
  const float* t_bv  = (const float*)d_in[24];
  const float* t_wo  = (const float*)d_in[25];
  const float* t_bo  = (const float*)d_in[26];
  const float* mn_g  = (const float*)d_in[27];
  const float* mn_b  = (const float*)d_in[28];
  const float* mw1   = (const float*)d_in[29];
  const float* mb1   = (const float*)d_in[30];
  const float* mw2   = (const float*)d_in[31];
  const float* mb2   = (const float*)d_in[32];
  const float* fn_g  = (const float*)d_in[33];
  const float* fn_b  = (const float*)d_in[34];

  float* ws = (float*)d_ws;
  const size_t NX = 4456448;           // B*T1*HW*D
  float* X   = ws;
  float* XN  = X  + NX;                // LN scratch / attn-out scratch
  float* Qb  = XN + NX;
  float* Kb  = Qb + NX;
  float* Vb  = Kb + NX;
  float* LT  = Vb + NX;                // 1,183,744 floats
  float* HID = Qb;                     // MLP hidden (8704x1024) aliases Qb+Kb (dead then)

  float* out0 = (float*)d_out;         // [B,T1,HW,D]
  float* out1 = out0 + NX;             // [B,HW,NH,T1,T1]
  float* out2 = out1 + 1183744;        // [6,512,8,16,64]
  float* out3 = out2 + 25165824;

  const int RS = B__*T_*HWL;           // 8192 spatial rows
  const int RT = B__*T1_*HWL;          // 8704 temporal rows
  dim3 gS(8,  RS/64);
  dim3 gT(8,  RT/64);
  dim3 gM(16, RT/64);

  embed_ln_kernel<<<RT/4, 256, 0, stream>>>(codes, emb, cls, hpos, wpos, eng, enb, X);

  for(int i=0;i<6;i++){
    const size_t wo = (size_t)i*D_*D_;
    // ---- spatial windowed attention ----
    ln_kernel<<<RS/4,256,0,stream>>>(X, XN, sn_g+i*D_, sn_b+i*D_, T_*HWL, T1_*HWL);
    gemm_kernel<0,false><<<gS,256,0,stream>>>(XN, s_wq+wo, s_bq+i*D_, Qb, nullptr, D_, D_, RS, RS);
    gemm_kernel<0,false><<<gS,256,0,stream>>>(XN, s_wk+wo, s_bk+i*D_, Kb, nullptr, D_, D_, RS, RS);
    gemm_kernel<0,false><<<gS,256,0,stream>>>(XN, s_wv+wo, s_bv+i*D_, Vb, nullptr, D_, D_, RS, RS);
    spatial_attn_kernel<<<RS,512,0,stream>>>(Qb, Kb, Vb, XN);
    gemm_kernel<0,true><<<gS,256,0,stream>>>(XN, s_wo+wo, s_bo+i*D_, X, X, D_, D_, T_*HWL, T1_*HWL);
    // ---- temporal RoPE causal attention ----
    ln_kernel<<<RT/4,256,0,stream>>>(X, XN, tn_g+i*D_, tn_b+i*D_, T1_*HWL, T1_*HWL);
    gemm_kernel<0,false><<<gT,256,0,stream>>>(XN, t_wq+wo, t_bq+i*D_, Qb, nullptr, D_, D_, RT, RT);
    gemm_kernel<0,false><<<gT,256,0,stream>>>(XN, t_wk+wo, t_bk+i*D_, Kb, nullptr, D_, D_, RT, RT);
    gemm_kernel<0,false><<<gT,256,0,stream>>>(XN, t_wv+wo, t_bv+i*D_, Vb, nullptr, D_, D_, RT, RT);
    rope_kernel<<<RT,256,0,stream>>>(Qb);
    rope_kernel<<<RT,256,0,stream>>>(Kb);
    export_kv_kernel<<<16384,256,0,stream>>>(Kb, Vb, out2+(size_t)i*4194304, out3+(size_t)i*4194304);
    float* ltp = (i==5) ? out1 : LT;
    temporal_logits_kernel<<<17408,256,0,stream>>>(Qb, Kb, ltp);
    temporal_av_kernel<<<17408,256,0,stream>>>(ltp, Vb, XN);
    gemm_kernel<0,true><<<gT,256,0,stream>>>(XN, t_wo+wo, t_bo+i*D_, X, X, D_, D_, RT, RT);
    avg_frame0_kernel<<<1024,256,0,stream>>>(X);
    // ---- MLP ----
    ln_kernel<<<RT/4,256,0,stream>>>(X, XN, mn_g+i*D_, mn_b+i*D_, T1_*HWL, T1_*HWL);
    gemm_kernel<1,false><<<gM,256,0,stream>>>(XN, mw1+(size_t)i*D_*1024, mb1+i*1024, HID, nullptr, D_, 1024, RT, RT);
    gemm_kernel<0,true><<<gT,256,0,stream>>>(HID, mw2+(size_t)i*1024*D_, mb2+i*D_, X, X, 1024, D_, RT, RT);
  }
  ln_kernel<<<RT/4,256,0,stream>>>(X, out0, fn_g, fn_b, T1_*HWL, T1_*HWL);
}

// Round 2
// 2601.656 us; speedup vs baseline: 2.4074x; 2.4074x over previous
//
#include <hip/hip_runtime.h>
#include <hip/hip_bf16.h>
#include <math.h>

#define D_    512
#define NHH   8
#define DH_   64
#define T_    16
#define T1_   17
#define HWL   256
#define B__   2
#define NEGV  -1e9f

typedef __attribute__((ext_vector_type(8))) short short8;
typedef __attribute__((ext_vector_type(4))) float f32x4;
typedef __hip_bfloat16 bf16;

__device__ inline float wave_sum(float v){
  #pragma unroll
  for(int o=32;o>0;o>>=1) v += __shfl_xor(v,o,64);
  return v;
}

__device__ inline void gload_lds16(const void* g, void* l){
  __builtin_amdgcn_global_load_lds((const __attribute__((address_space(1))) void*)g,
                                   (__attribute__((address_space(3))) void*)l, 16, 0, 0);
}

// ---------------- embedding + LN  (rows = B*T1*HW, one wave per row) ----------------
__global__ __launch_bounds__(256) void embed_ln_kernel(
    const int* __restrict__ codes, const float* __restrict__ emb,
    const float* __restrict__ cls, const float* __restrict__ hpos,
    const float* __restrict__ wpos, const float* __restrict__ g,
    const float* __restrict__ bta, float* __restrict__ X){
  int row  = blockIdx.x*4 + (threadIdx.x>>6);
  int lane = threadIdx.x & 63;
  int hw = row % HWL; int bt = row / HWL; int t = bt % T1_; int bb = bt / T1_;
  float v[8];
  if(t < T_){
    int code = codes[(bb*T_ + t)*HWL + hw];
    const float* ep = emb  + (size_t)code*D_;
    const float* hp = hpos + (size_t)(hw & 15)*D_;
    const float* wp = wpos + (size_t)(hw >> 4)*D_;
    #pragma unroll
    for(int j=0;j<8;j++){ int d = lane + j*64; v[j] = ep[d] + hp[d] + wp[d]; }
  } else {
    #pragma unroll
    for(int j=0;j<8;j++) v[j] = cls[lane + j*64];
  }
  float s=0;
  #pragma unroll
  for(int j=0;j<8;j++) s += v[j];
  s = wave_sum(s);
  float mean = s*(1.f/512.f);
  float s2=0;
  #pragma unroll
  for(int j=0;j<8;j++){ float d0=v[j]-mean; s2 += d0*d0; }
  s2 = wave_sum(s2);
  float inv = rsqrtf(s2*(1.f/512.f) + 1e-5f);
  float* o = X + (size_t)row*D_;
  #pragma unroll
  for(int j=0;j<8;j++){ int d = lane + j*64; o[d] = (v[j]-mean)*inv*g[d] + bta[d]; }
}

// ---------------- LayerNorm, fp32 out (final) ----------------
__global__ __launch_bounds__(256) void ln_kernel(
    const float* __restrict__ in, float* __restrict__ out,
    const float* __restrict__ g, const float* __restrict__ bta,
    int c_rpb, int s_rpb){
  int row  = blockIdx.x*4 + (threadIdx.x>>6);
  int lane = threadIdx.x & 63;
  int bb = row / c_rpb; int rem = row - bb*c_rpb;
  const float* p = in + ((size_t)bb*s_rpb + rem)*D_;
  float v[8]; float s=0;
  #pragma unroll
  for(int j=0;j<8;j++){ v[j] = p[lane + j*64]; s += v[j]; }
  s = wave_sum(s);
  float mean = s*(1.f/512.f);
  float s2=0;
  #pragma unroll
  for(int j=0;j<8;j++){ float d0=v[j]-mean; s2 += d0*d0; }
  s2 = wave_sum(s2);
  float inv = rsqrtf(s2*(1.f/512.f) + 1e-5f);
  float* o = out + (size_t)row*D_;
  #pragma unroll
  for(int j=0;j<8;j++){ int d = lane + j*64; o[d] = (v[j]-mean)*inv*g[d] + bta[d]; }
}

// ---------------- LayerNorm, bf16 out (GEMM A producer) ----------------
__global__ __launch_bounds__(256) void ln_bf_kernel(
    const float* __restrict__ in, bf16* __restrict__ out,
    const float* __restrict__ g, const float* __restrict__ bta,
    int c_rpb, int s_rpb){
  int row  = blockIdx.x*4 + (threadIdx.x>>6);
  int lane = threadIdx.x & 63;
  int bb = row / c_rpb; int rem = row - bb*c_rpb;
  const float* p = in + ((size_t)bb*s_rpb + rem)*D_;
  float v[8]; float s=0;
  #pragma unroll
  for(int j=0;j<8;j++){ v[j] = p[lane + j*64]; s += v[j]; }
  s = wave_sum(s);
  float mean = s*(1.f/512.f);
  float s2=0;
  #pragma unroll
  for(int j=0;j<8;j++){ float d0=v[j]-mean; s2 += d0*d0; }
  s2 = wave_sum(s2);
  float inv = rsqrtf(s2*(1.f/512.f) + 1e-5f);
  bf16* o = out + (size_t)row*D_;
  #pragma unroll
  for(int j=0;j<8;j++){ int d = lane + j*64; o[d] = __float2bfloat16((v[j]-mean)*inv*g[d] + bta[d]); }
}

// ---------------- weight fp32[K][N] -> bf16[N][K] transpose+convert, 10 mats/layer ----------------
__global__ __launch_bounds__(256) void wconv_kernel(
    const float* sq, const float* sk, const float* sv, const float* so,
    const float* tq, const float* tk, const float* tv, const float* to,
    const float* w1, const float* w2, bf16* __restrict__ dst){
  __shared__ float sm[32][33];
  int id = blockIdx.z;
  const float* src; bf16* d; int K, N;
  switch(id){
    case 0: src=sq; d=dst+0*262144;  K=512;  N=512;  break;
    case 1: src=sk; d=dst+1*262144;  K=512;  N=512;  break;
    case 2: src=sv; d=dst+2*262144;  K=512;  N=512;  break;
    case 3: src=so; d=dst+3*262144;  K=512;  N=512;  break;
    case 4: src=tq; d=dst+4*262144;  K=512;  N=512;  break;
    case 5: src=tk; d=dst+5*262144;  K=512;  N=512;  break;
    case 6: src=tv; d=dst+6*262144;  K=512;  N=512;  break;
    case 7: src=to; d=dst+7*262144;  K=512;  N=512;  break;
    case 8: src=w1; d=dst+2097152;   K=512;  N=1024; break;
    default:src=w2; d=dst+2621440;   K=1024; N=512;  break;
  }
  int n0 = blockIdx.x<<5, k0 = blockIdx.y<<5;
  if(n0 >= N || k0 >= K) return;
  int tx = threadIdx.x & 31, ty = threadIdx.x >> 5;
  #pragma unroll
  for(int j=0;j<4;j++) sm[ty+j*8][tx] = src[(size_t)(k0+ty+j*8)*N + n0+tx];
  __syncthreads();
  #pragma unroll
  for(int j=0;j<4;j++) d[(size_t)(n0+ty+j*8)*K + k0+tx] = __float2bfloat16(sm[tx][ty+j*8]);
}

// ---------------- bf16 MFMA GEMM: out = act(A @ Wt^T + bias) [+resid] ----------------
// A: [M][K] bf16 row-major. Wt: [N][K] bf16 (pre-transposed weights).
// 128x128 tile, BK=32, 4 waves (2x2 of 64x64), global_load_lds staging.
template<int ACT, bool RES, bool OBF>
__global__ __launch_bounds__(256) void gemm_mfma(
    const bf16* __restrict__ A, const bf16* __restrict__ Wt,
    const float* __restrict__ bias, void* __restrict__ outp,
    const float* __restrict__ resid, int K, int N, int c_rpb, int o_rpb){
  __shared__ __align__(16) bf16 As[128*32];
  __shared__ __align__(16) bf16 Bs[128*32];
  const int tid  = threadIdx.x;
  const int lane = tid & 63;
  const int w    = tid >> 6;
  const int row0 = blockIdx.y << 7;
  const int col0 = blockIdx.x << 7;
  const int mb = (w>>1)*64, nb = (w&1)*64;

  // staging chunk geometry: 512 chunks of 16B per tile, chunk c -> row c>>2, kofs (c&3)*8
  const int c0 = w*64 + lane;
  const int c1 = c0 + 256;
  const size_t ga0 = (size_t)(row0 + (c0>>2))*K + ((c0&3)<<3);
  const size_t ga1 = (size_t)(row0 + (c1>>2))*K + ((c1&3)<<3);
  const size_t gb0 = (size_t)(col0 + (c0>>2))*K + ((c0&3)<<3);
  const size_t gb1 = (size_t)(col0 + (c1>>2))*K + ((c1&3)<<3);

  f32x4 acc[4][4] = {};
  for(int k0=0;k0<K;k0+=32){
    gload_lds16(A  + ga0 + k0, As + (size_t)w*512);
    gload_lds16(A  + ga1 + k0, As + (size_t)(4+w)*512);
    gload_lds16(Wt + gb0 + k0, Bs + (size_t)w*512);
    gload_lds16(Wt + gb1 + k0, Bs + (size_t)(4+w)*512);
    __syncthreads();
    const short8* Av = (const short8*)As;
    const short8* Bv = (const short8*)Bs;
    short8 af[4], bfr[4];
    #pragma unroll
    for(int mi=0;mi<4;mi++) af[mi]  = Av[(mb + mi*16 + (lane&15))*4 + (lane>>4)];
    #pragma unroll
    for(int ni=0;ni<4;ni++) bfr[ni] = Bv[(nb + ni*16 + (lane&15))*4 + (lane>>4)];
    #pragma unroll
    for(int mi=0;mi<4;mi++)
      #pragma unroll
      for(int ni=0;ni<4;ni++)
        acc[mi][ni] = __builtin_amdgcn_mfma_f32_16x16x32_bf16(af[mi], bfr[ni], acc[mi][ni], 0,0,0);
    __syncthreads();
  }
  #pragma unroll
  for(int mi=0;mi<4;mi++){
    #pragma unroll
    for(int r=0;r<4;r++){
      int row = row0 + mb + mi*16 + (lane>>4)*4 + r;
      int bb = row / c_rpb;
      size_t orow = (size_t)bb*o_rpb + (row - bb*c_rpb);
      #pragma unroll
      for(int ni=0;ni<4;ni++){
        int col = col0 + nb + ni*16 + (lane&15);
        float v = acc[mi][ni][r] + bias[col];
        if(ACT==1) v = tanhf(v);
        if(RES) v += resid[orow*(size_t)N + col];
        if(OBF) ((bf16*)outp)[orow*(size_t)N + col] = __float2bfloat16(v);
        else    ((float*)outp)[orow*(size_t)N + col] = v;
      }
    }
  }
}

// ---------------- spatial 3x3 windowed attention (wave per (loc,head)), bf16 out ----------------
__global__ __launch_bounds__(512) void spatial_attn_kernel(
    const float* __restrict__ Q, const float* __restrict__ K,
    const float* __restrict__ V, bf16* __restrict__ O){
  int loc = blockIdx.x;
  int hw = loc & 255;
  int hh = hw >> 4, ww = hw & 15;
  int head = threadIdx.x >> 6, dh = threadIdx.x & 63;
  size_t cbase = (size_t)loc*D_ + head*DH_ + dh;
  float q = Q[cbase];
  float lg[9];
  int nrow[9];
  #pragma unroll
  for(int s=0;s<9;s++){
    int a = s/3 - 1, b2 = s%3 - 1;
    int nh = hh + a, nw = ww + b2;
    bool ok = ((unsigned)nh < 16u) && ((unsigned)nw < 16u);
    nrow[s] = ok ? (loc - hw + (nh<<4) + nw) : -1;
    float partial = ok ? q * K[(size_t)nrow[s]*D_ + head*DH_ + dh] : 0.f;
    float dot = wave_sum(partial);
    lg[s] = ok ? dot*0.125f : NEGV;
  }
  float m = lg[0];
  #pragma unroll
  for(int s=1;s<9;s++) m = fmaxf(m, lg[s]);
  float den = 0.f, wv[9];
  #pragma unroll
  for(int s=0;s<9;s++){ wv[s] = __expf(lg[s]-m); den += wv[s]; }
  float inv = 1.f/den;
  float acc = 0.f;
  #pragma unroll
  for(int s=0;s<9;s++){
    if(nrow[s] >= 0) acc += wv[s] * V[(size_t)nrow[s]*D_ + head*DH_ + dh];
  }
  O[cbase] = __float2bfloat16(acc*inv);
}

// ---------------- RoPE (in place) ----------------
__global__ __launch_bounds__(256) void rope_kernel(float* __restrict__ X){
  int gid = blockIdx.x*256 + threadIdx.x;
  int pair = gid & 255; int row = gid >> 8;
  int t = (row >> 8) % T1_;
  int h = pair >> 5, i = pair & 31;
  float* p = X + (size_t)row*D_ + h*DH_;
  float x1 = p[i], x2 = p[i+32];
  float freq = __expf(-9.210340372f * (float)i * (1.f/32.f));
  float ang = (float)t * freq;
  float c = cosf(ang), sn = sinf(ang);
  p[i]    = x1*c - x2*sn;
  p[i+32] = x2*c + x1*sn;
}

// ---------------- export roped K / V (frames 0..15) ----------------
__global__ __launch_bounds__(256) void export_kv_kernel(
    const float* __restrict__ KT, const float* __restrict__ VT,
    float* __restrict__ kout, float* __restrict__ vout){
  int gid = blockIdx.x*256 + threadIdx.x;
  int dh = gid & 63; int r = gid >> 6;
  int t = r & 15; r >>= 4; int h = r & 7; r >>= 3; int hw = r & 255; int bb = r >> 8;
  size_t src = ((size_t)(bb*T1_ + t)*HWL + hw)*D_ + h*DH_ + dh;
  kout[gid] = KT[src];
  vout[gid] = VT[src];
}

// ---------------- temporal masked logits ----------------
__global__ __launch_bounds__(256) void temporal_logits_kernel(
    const float* __restrict__ QT, const float* __restrict__ KT, float* __restrict__ LT){
  int wid  = (blockIdx.x << 2) + (threadIdx.x >> 6);
  int lane = threadIdx.x & 63;
  int t = wid % T1_; int r = wid / T1_;
  int h = r & 7; r >>= 3; int hw = r & 255; int bb = r >> 8;
  if(lane >= T1_) return;
  int u = lane;
  const float* qp = QT + ((size_t)(bb*T1_ + t)*HWL + hw)*D_ + h*DH_;
  const float* kp = KT + ((size_t)(bb*T1_ + u)*HWL + hw)*D_ + h*DH_;
  float dot = 0.f;
  #pragma unroll
  for(int d=0; d<DH_; d++) dot += qp[d]*kp[d];
  bool masked = (u > t) || (t == T_ && u == T_);
  LT[((((size_t)bb*HWL + hw)*NHH + h)*T1_ + t)*T1_ + u] = masked ? NEGV : dot*0.125f;
}

// ---------------- temporal softmax + A@V, bf16 out ----------------
__global__ __launch_bounds__(256) void temporal_av_kernel(
    const float* __restrict__ LT, const float* __restrict__ VT, bf16* __restrict__ OT){
  int wid  = (blockIdx.x << 2) + (threadIdx.x >> 6);
  int lane = threadIdx.x & 63;
  int t = wid % T1_; int r = wid / T1_;
  int h = r & 7; r >>= 3; int hw = r & 255; int bb = r >> 8;
  const float* lp = LT + ((((size_t)bb*HWL + hw)*NHH + h)*T1_ + t)*T1_;
  float lg[T1_];
  float m = -1e30f;
  #pragma unroll
  for(int u=0;u<T1_;u++){ lg[u] = lp[u]; m = fmaxf(m, lg[u]); }
  float den = 0.f;
  #pragma unroll
  for(int u=0;u<T1_;u++){ lg[u] = __expf(lg[u]-m); den += lg[u]; }
  float inv = 1.f/den;
  float acc = 0.f;
  #pragma unroll
  for(int u=0;u<T1_;u++){
    acc += lg[u] * VT[((size_t)(bb*T1_ + u)*HWL + hw)*D_ + h*DH_ + lane];
  }
  OT[((size_t)(bb*T1_ + t)*HWL + hw)*D_ + h*DH_ + lane] = __float2bfloat16(acc*inv);
}

// ---------------- frame-0 spatial mean broadcast ----------------
__global__ __launch_bounds__(256) void avg_frame0_kernel(float* __restrict__ X){
  int d = blockIdx.x & 511; int bb = blockIdx.x >> 9;
  int hw = threadIdx.x;
  __shared__ float sm[256];
  size_t idx = ((size_t)(bb*T1_)*HWL + hw)*D_ + d;
  sm[hw] = X[idx];
  __syncthreads();
  for(int o=128;o>0;o>>=1){ if(hw<o) sm[hw] += sm[hw+o]; __syncthreads(); }
  X[idx] = sm[0]*(1.f/256.f);
}

extern "C" void kernel_launch(void* const* d_in, const int* in_sizes, int n_in,
                              void* d_out, int out_size, void* d_ws, size_t ws_size,
                              hipStream_t stream){
  const int*   codes = (const int*)  d_in[0];
  const float* emb   = (const float*)d_in[1];
  const float* cls   = (const float*)d_in[2];
  const float* hpos  = (const float*)d_in[3];
  const float* wpos  = (const float*)d_in[4];
  const float* eng   = (const float*)d_in[5];
  const float* enb   = (const float*)d_in[6];
  const float* sn_g  = (const float*)d_in[7];
  const float* sn_b  = (const float*)d_in[8];
  const float* s_wq  = (const float*)d_in[9];
  const float* s_bq  = (const float*)d_in[10];
  const float* s_wk  = (const float*)d_in[11];
  const float* s_bk  = (const float*)d_in[12];
  const float* s_wv  = (const float*)d_in[13];
  const float* s_bv  = (const float*)d_in[14];
  const float* s_wo  = (const float*)d_in[15];
  const float* s_bo  = (const float*)d_in[16];
  const float* tn_g  = (const float*)d_in[17];
  const float* tn_b  = (const float*)d_in[18];
  const float* t_wq  = (const float*)d_in[19];
  const float* t_bq  = (const float*)d_in[20];
  const float* t_wk  = (const float*)d_in[21];
  const float* t_bk  = (const float*)d_in[22];
  const float* t_wv  = (const float*)d_in[23];
  const float* t_bv  = (const float*)d_in[24];
  const float* t_wo  = (const float*)d_in[25];
  const float* t_bo  = (const float*)d_in[26];
  const float* mn_g  = (const float*)d_in[27];
  const float* mn_b  = (const float*)d_in[28];
  const float* mw1   = (const float*)d_in[29];
  const float* mb1   = (const float*)d_in[30];
  const float* mw2   = (const float*)d_in[31];
  const float* mb2   = (const float*)d_in[32];
  const float* fn_g  = (const float*)d_in[33];
  const float* fn_b  = (const float*)d_in[34];

  float* ws = (float*)d_ws;
  const size_t NX = 4456448;           // B*T1*HW*D
  float* X   = ws;
  float* Qb  = X  + NX;
  float* Kb  = Qb + NX;
  float* Vb  = Kb + NX;
  float* LT  = Vb + NX;                // 1,183,744 floats
  bf16*  XNb = (bf16*)(LT + 1183744);  // B*T1*HW*D bf16  (2,228,224 floats)
  bf16*  Wt  = (bf16*)(LT + 1183744 + 2228224); // 3,145,728 bf16 (1,572,864 floats)
  bf16*  HIDb= (bf16*)Qb;              // MLP hidden [8704][1024] bf16, aliases Qb

  float* out0 = (float*)d_out;
  float* out1 = out0 + NX;
  float* out2 = out1 + 1183744;
  float* out3 = out2 + 25165824;

  const int RS = B__*T_*HWL;           // 8192
  const int RT = B__*T1_*HWL;          // 8704
  dim3 gS(4, 64);                      // spatial D->D GEMM (M=8192, N=512)
  dim3 gT(4, 68);                      // temporal D->D (M=8704)
  dim3 gM1(8, 68);                     // MLP1 (N=1024)
  dim3 gM2(4, 68);                     // MLP2 (K=1024, N=512)
  dim3 wcg(32, 32, 10);

  embed_ln_kernel<<<RT/4, 256, 0, stream>>>(codes, emb, cls, hpos, wpos, eng, enb, X);

  for(int i=0;i<6;i++){
    const size_t wo = (size_t)i*D_*D_;
    wconv_kernel<<<wcg,256,0,stream>>>(s_wq+wo, s_wk+wo, s_wv+wo, s_wo+wo,
                                       t_wq+wo, t_wk+wo, t_wv+wo, t_wo+wo,
                                       mw1+(size_t)i*524288, mw2+(size_t)i*524288, Wt);
    // ---- spatial windowed attention ----
    ln_bf_kernel<<<RS/4,256,0,stream>>>(X, XNb, sn_g+i*D_, sn_b+i*D_, T_*HWL, T1_*HWL);
    gemm_mfma<0,false,false><<<gS,256,0,stream>>>(XNb, Wt+0*262144, s_bq+i*D_, Qb, nullptr, 512, 512, RS, RS);
    gemm_mfma<0,false,false><<<gS,256,0,stream>>>(XNb, Wt+1*262144, s_bk+i*D_, Kb, nullptr, 512, 512, RS, RS);
    gemm_mfma<0,false,false><<<gS,256,0,stream>>>(XNb, Wt+2*262144, s_bv+i*D_, Vb, nullptr, 512, 512, RS, RS);
    spatial_attn_kernel<<<RS,512,0,stream>>>(Qb, Kb, Vb, XNb);
    gemm_mfma<0,true,false><<<gS,256,0,stream>>>(XNb, Wt+3*262144, s_bo+i*D_, X, X, 512, 512, T_*HWL, T1_*HWL);
    // ---- temporal RoPE causal attention ----
    ln_bf_kernel<<<RT/4,256,0,stream>>>(X, XNb, tn_g+i*D_, tn_b+i*D_, T1_*HWL, T1_*HWL);
    gemm_mfma<0,false,false><<<gT,256,0,stream>>>(XNb, Wt+4*262144, t_bq+i*D_, Qb, nullptr, 512, 512, RT, RT);
    gemm_mfma<0,false,false><<<gT,256,0,stream>>>(XNb, Wt+5*262144, t_bk+i*D_, Kb, nullptr, 512, 512, RT, RT);
    gemm_mfma<0,false,false><<<gT,256,0,stream>>>(XNb, Wt+6*262144, t_bv+i*D_, Vb, nullptr, 512, 512, RT, RT);
    rope_kernel<<<RT,256,0,stream>>>(Qb);
    rope_kernel<<<RT,256,0,stream>>>(Kb);
    export_kv_kernel<<<16384,256,0,stream>>>(Kb, Vb, out2+(size_t)i*4194304, out3+(size_t)i*4194304);
    float* ltp = (i==5) ? out1 : LT;
    temporal_logits_kernel<<<17408,256,0,stream>>>(Qb, Kb, ltp);
    temporal_av_kernel<<<17408,256,0,stream>>>(ltp, Vb, XNb);
    gemm_mfma<0,true,false><<<gT,256,0,stream>>>(XNb, Wt+7*262144, t_bo+i*D_, X, X, 512, 512, RT, RT);
    avg_frame0_kernel<<<1024,256,0,stream>>>(X);
    // ---- MLP ----
    ln_bf_kernel<<<RT/4,256,0,stream>>>(X, XNb, mn_g+i*D_, mn_b+i*D_, T1_*HWL, T1_*HWL);
    gemm_mfma<1,false,true ><<<gM1,256,0,stream>>>(XNb, Wt+2097152, mb1+i*1024, HIDb, nullptr, 512, 1024, RT, RT);
    gemm_mfma<0,true,false><<<gM2,256,0,stream>>>(HIDb, Wt+2621440, mb2+i*D_, X, X, 1024, 512, RT, RT);
  }
  ln_kernel<<<RT/4,256,0,stream>>>(X, out0, fn_g, fn_b, T1_*HWL, T1_*HWL);
}

// Round 3
// 1629.899 us; speedup vs baseline: 3.8427x; 1.5962x over previous
//
#include <hip/hip_runtime.h>
#include <hip/hip_bf16.h>
#include <math.h>

#define D_    512
#define NHH   8
#define DH_   64
#define T_    16
#define T1_   17
#define HWL   256
#define B__   2
#define NEGV  -1e9f

typedef __attribute__((ext_vector_type(8))) short short8;
typedef __attribute__((ext_vector_type(4))) float f32x4;
typedef __hip_bfloat16 bf16;

__device__ inline float wave_sum(float v){
  #pragma unroll
  for(int o=32;o>0;o>>=1) v += __shfl_xor(v,o,64);
  return v;
}

__device__ inline void gload_lds16(const void* g, void* l){
  __builtin_amdgcn_global_load_lds((const __attribute__((address_space(1))) void*)g,
                                   (__attribute__((address_space(3))) void*)l, 16, 0, 0);
}

// ---------------- embedding + LN ----------------
__global__ __launch_bounds__(256) void embed_ln_kernel(
    const int* __restrict__ codes, const float* __restrict__ emb,
    const float* __restrict__ cls, const float* __restrict__ hpos,
    const float* __restrict__ wpos, const float* __restrict__ g,
    const float* __restrict__ bta, float* __restrict__ X){
  int row  = blockIdx.x*4 + (threadIdx.x>>6);
  int lane = threadIdx.x & 63;
  int hw = row % HWL; int bt = row / HWL; int t = bt % T1_; int bb = bt / T1_;
  float v[8];
  if(t < T_){
    int code = codes[(bb*T_ + t)*HWL + hw];
    const float* ep = emb  + (size_t)code*D_;
    const float* hp = hpos + (size_t)(hw & 15)*D_;
    const float* wp = wpos + (size_t)(hw >> 4)*D_;
    #pragma unroll
    for(int j=0;j<8;j++){ int d = lane + j*64; v[j] = ep[d] + hp[d] + wp[d]; }
  } else {
    #pragma unroll
    for(int j=0;j<8;j++) v[j] = cls[lane + j*64];
  }
  float s=0;
  #pragma unroll
  for(int j=0;j<8;j++) s += v[j];
  s = wave_sum(s);
  float mean = s*(1.f/512.f);
  float s2=0;
  #pragma unroll
  for(int j=0;j<8;j++){ float d0=v[j]-mean; s2 += d0*d0; }
  s2 = wave_sum(s2);
  float inv = rsqrtf(s2*(1.f/512.f) + 1e-5f);
  float* o = X + (size_t)row*D_;
  #pragma unroll
  for(int j=0;j<8;j++){ int d = lane + j*64; o[d] = (v[j]-mean)*inv*g[d] + bta[d]; }
}

// ---------------- LayerNorm, fp32 out (final) ----------------
__global__ __launch_bounds__(256) void ln_kernel(
    const float* __restrict__ in, float* __restrict__ out,
    const float* __restrict__ g, const float* __restrict__ bta,
    int c_rpb, int s_rpb){
  int row  = blockIdx.x*4 + (threadIdx.x>>6);
  int lane = threadIdx.x & 63;
  int bb = row / c_rpb; int rem = row - bb*c_rpb;
  const float* p = in + ((size_t)bb*s_rpb + rem)*D_;
  float v[8]; float s=0;
  #pragma unroll
  for(int j=0;j<8;j++){ v[j] = p[lane + j*64]; s += v[j]; }
  s = wave_sum(s);
  float mean = s*(1.f/512.f);
  float s2=0;
  #pragma unroll
  for(int j=0;j<8;j++){ float d0=v[j]-mean; s2 += d0*d0; }
  s2 = wave_sum(s2);
  float inv = rsqrtf(s2*(1.f/512.f) + 1e-5f);
  float* o = out + (size_t)row*D_;
  #pragma unroll
  for(int j=0;j<8;j++){ int d = lane + j*64; o[d] = (v[j]-mean)*inv*g[d] + bta[d]; }
}

// ---------------- LayerNorm, bf16 out ----------------
__global__ __launch_bounds__(256) void ln_bf_kernel(
    const float* __restrict__ in, bf16* __restrict__ out,
    const float* __restrict__ g, const float* __restrict__ bta,
    int c_rpb, int s_rpb){
  int row  = blockIdx.x*4 + (threadIdx.x>>6);
  int lane = threadIdx.x & 63;
  int bb = row / c_rpb; int rem = row - bb*c_rpb;
  const float* p = in + ((size_t)bb*s_rpb + rem)*D_;
  float v[8]; float s=0;
  #pragma unroll
  for(int j=0;j<8;j++){ v[j] = p[lane + j*64]; s += v[j]; }
  s = wave_sum(s);
  float mean = s*(1.f/512.f);
  float s2=0;
  #pragma unroll
  for(int j=0;j<8;j++){ float d0=v[j]-mean; s2 += d0*d0; }
  s2 = wave_sum(s2);
  float inv = rsqrtf(s2*(1.f/512.f) + 1e-5f);
  bf16* o = out + (size_t)row*D_;
  #pragma unroll
  for(int j=0;j<8;j++){ int d = lane + j*64; o[d] = __float2bfloat16((v[j]-mean)*inv*g[d] + bta[d]); }
}

// ---------------- weight fp32[K][N] -> bf16[N][K] ----------------
__global__ __launch_bounds__(256) void wconv_kernel(
    const float* sq, const float* sk, const float* sv, const float* so,
    const float* tq, const float* tk, const float* tv, const float* to,
    const float* w1, const float* w2, bf16* __restrict__ dst){
  __shared__ float sm[32][33];
  int id = blockIdx.z;
  const float* src; bf16* d; int K, N;
  switch(id){
    case 0: src=sq; d=dst+0*262144;  K=512;  N=512;  break;
    case 1: src=sk; d=dst+1*262144;  K=512;  N=512;  break;
    case 2: src=sv; d=dst+2*262144;  K=512;  N=512;  break;
    case 3: src=so; d=dst+3*262144;  K=512;  N=512;  break;
    case 4: src=tq; d=dst+4*262144;  K=512;  N=512;  break;
    case 5: src=tk; d=dst+5*262144;  K=512;  N=512;  break;
    case 6: src=tv; d=dst+6*262144;  K=512;  N=512;  break;
    case 7: src=to; d=dst+7*262144;  K=512;  N=512;  break;
    case 8: src=w1; d=dst+2097152;   K=512;  N=1024; break;
    default:src=w2; d=dst+2621440;   K=1024; N=512;  break;
  }
  int n0 = blockIdx.x<<5, k0 = blockIdx.y<<5;
  if(n0 >= N || k0 >= K) return;
  int tx = threadIdx.x & 31, ty = threadIdx.x >> 5;
  #pragma unroll
  for(int j=0;j<4;j++) sm[ty+j*8][tx] = src[(size_t)(k0+ty+j*8)*N + n0+tx];
  __syncthreads();
  #pragma unroll
  for(int j=0;j<4;j++) d[(size_t)(n0+ty+j*8)*K + k0+tx] = __float2bfloat16(sm[tx][ty+j*8]);
}

// ---------------- bf16 MFMA GEMM (single output) ----------------
template<int ACT, bool RES, bool OBF>
__global__ __launch_bounds__(256) void gemm_mfma(
    const bf16* __restrict__ A, const bf16* __restrict__ Wt,
    const float* __restrict__ bias, void* __restrict__ outp,
    const float* __restrict__ resid, int K, int N, int c_rpb, int o_rpb){
  __shared__ __align__(16) bf16 As[128*32];
  __shared__ __align__(16) bf16 Bs[128*32];
  const int tid  = threadIdx.x;
  const int lane = tid & 63;
  const int w    = tid >> 6;
  const int row0 = blockIdx.y << 7;
  const int col0 = blockIdx.x << 7;
  const int mb = (w>>1)*64, nb = (w&1)*64;
  const int c0 = w*64 + lane;
  const int c1 = c0 + 256;
  const size_t ga0 = (size_t)(row0 + (c0>>2))*K + ((c0&3)<<3);
  const size_t ga1 = (size_t)(row0 + (c1>>2))*K + ((c1&3)<<3);
  const size_t gb0 = (size_t)(col0 + (c0>>2))*K + ((c0&3)<<3);
  const size_t gb1 = (size_t)(col0 + (c1>>2))*K + ((c1&3)<<3);

  f32x4 acc[4][4] = {};
  for(int k0=0;k0<K;k0+=32){
    gload_lds16(A  + ga0 + k0, As + (size_t)w*512);
    gload_lds16(A  + ga1 + k0, As + (size_t)(4+w)*512);
    gload_lds16(Wt + gb0 + k0, Bs + (size_t)w*512);
    gload_lds16(Wt + gb1 + k0, Bs + (size_t)(4+w)*512);
    __syncthreads();
    const short8* Av = (const short8*)As;
    const short8* Bv = (const short8*)Bs;
    short8 af[4], bfr[4];
    #pragma unroll
    for(int mi=0;mi<4;mi++) af[mi]  = Av[(mb + mi*16 + (lane&15))*4 + (lane>>4)];
    #pragma unroll
    for(int ni=0;ni<4;ni++) bfr[ni] = Bv[(nb + ni*16 + (lane&15))*4 + (lane>>4)];
    #pragma unroll
    for(int mi=0;mi<4;mi++)
      #pragma unroll
      for(int ni=0;ni<4;ni++)
        acc[mi][ni] = __builtin_amdgcn_mfma_f32_16x16x32_bf16(af[mi], bfr[ni], acc[mi][ni], 0,0,0);
    __syncthreads();
  }
  #pragma unroll
  for(int mi=0;mi<4;mi++){
    #pragma unroll
    for(int r=0;r<4;r++){
      int row = row0 + mb + mi*16 + (lane>>4)*4 + r;
      int bb = row / c_rpb;
      size_t orow = (size_t)bb*o_rpb + (row - bb*c_rpb);
      #pragma unroll
      for(int ni=0;ni<4;ni++){
        int col = col0 + nb + ni*16 + (lane&15);
        float v = acc[mi][ni][r] + bias[col];
        if(ACT==1) v = tanhf(v);
        if(RES) v += resid[orow*(size_t)N + col];
        if(OBF) ((bf16*)outp)[orow*(size_t)N + col] = __float2bfloat16(v);
        else    ((float*)outp)[orow*(size_t)N + col] = v;
      }
    }
  }
}

// ---------------- fused QKV GEMM: N=1536 (Wq|Wk|Wv rows contiguous), bf16 outs ----------------
__global__ __launch_bounds__(256) void gemm_qkv(
    const bf16* __restrict__ A, const bf16* __restrict__ Wt,
    const float* __restrict__ bq, const float* __restrict__ bk, const float* __restrict__ bv,
    bf16* __restrict__ Qo, bf16* __restrict__ Ko, bf16* __restrict__ Vo){
  const int K = 512;
  __shared__ __align__(16) bf16 As[128*32];
  __shared__ __align__(16) bf16 Bs[128*32];
  const int tid  = threadIdx.x;
  const int lane = tid & 63;
  const int w    = tid >> 6;
  const int row0 = blockIdx.y << 7;
  const int col0 = blockIdx.x << 7;
  const int mb = (w>>1)*64, nb = (w&1)*64;
  const int c0 = w*64 + lane;
  const int c1 = c0 + 256;
  const size_t ga0 = (size_t)(row0 + (c0>>2))*K + ((c0&3)<<3);
  const size_t ga1 = (size_t)(row0 + (c1>>2))*K + ((c1&3)<<3);
  const size_t gb0 = (size_t)(col0 + (c0>>2))*K + ((c0&3)<<3);
  const size_t gb1 = (size_t)(col0 + (c1>>2))*K + ((c1&3)<<3);

  f32x4 acc[4][4] = {};
  for(int k0=0;k0<K;k0+=32){
    gload_lds16(A  + ga0 + k0, As + (size_t)w*512);
    gload_lds16(A  + ga1 + k0, As + (size_t)(4+w)*512);
    gload_lds16(Wt + gb0 + k0, Bs + (size_t)w*512);
    gload_lds16(Wt + gb1 + k0, Bs + (size_t)(4+w)*512);
    __syncthreads();
    const short8* Av = (const short8*)As;
    const short8* Bv = (const short8*)Bs;
    short8 af[4], bfr[4];
    #pragma unroll
    for(int mi=0;mi<4;mi++) af[mi]  = Av[(mb + mi*16 + (lane&15))*4 + (lane>>4)];
    #pragma unroll
    for(int ni=0;ni<4;ni++) bfr[ni] = Bv[(nb + ni*16 + (lane&15))*4 + (lane>>4)];
    #pragma unroll
    for(int mi=0;mi<4;mi++)
      #pragma unroll
      for(int ni=0;ni<4;ni++)
        acc[mi][ni] = __builtin_amdgcn_mfma_f32_16x16x32_bf16(af[mi], bfr[ni], acc[mi][ni], 0,0,0);
    __syncthreads();
  }
  const int sel = col0 >> 9;
  bf16* outp = (sel==0) ? Qo : (sel==1 ? Ko : Vo);
  const float* bp = (sel==0) ? bq : (sel==1 ? bk : bv);
  const int cb = col0 & 511;
  #pragma unroll
  for(int mi=0;mi<4;mi++){
    #pragma unroll
    for(int r=0;r<4;r++){
      int row = row0 + mb + mi*16 + (lane>>4)*4 + r;
      #pragma unroll
      for(int ni=0;ni<4;ni++){
        int col = cb + nb + ni*16 + (lane&15);
        outp[(size_t)row*512 + col] = __float2bfloat16(acc[mi][ni][r] + bp[col]);
      }
    }
  }
}

// ---------------- spatial 3x3 windowed attention, bf16 in/out ----------------
__global__ __launch_bounds__(512) void spatial_attn_kernel(
    const bf16* __restrict__ Q, const bf16* __restrict__ K,
    const bf16* __restrict__ V, bf16* __restrict__ O){
  int loc = blockIdx.x;
  int hw = loc & 255;
  int hh = hw >> 4, ww = hw & 15;
  int head = threadIdx.x >> 6, dh = threadIdx.x & 63;
  size_t cbase = (size_t)loc*D_ + head*DH_ + dh;
  float q = __bfloat162float(Q[cbase]);
  float lg[9];
  int nrow[9];
  #pragma unroll
  for(int s=0;s<9;s++){
    int a = s/3 - 1, b2 = s%3 - 1;
    int nh = hh + a, nw = ww + b2;
    bool ok = ((unsigned)nh < 16u) && ((unsigned)nw < 16u);
    nrow[s] = ok ? (loc - hw + (nh<<4) + nw) : -1;
    float partial = ok ? q * __bfloat162float(K[(size_t)nrow[s]*D_ + head*DH_ + dh]) : 0.f;
    float dot = wave_sum(partial);
    lg[s] = ok ? dot*0.125f : NEGV;
  }
  float m = lg[0];
  #pragma unroll
  for(int s=1;s<9;s++) m = fmaxf(m, lg[s]);
  float den = 0.f, wv[9];
  #pragma unroll
  for(int s=0;s<9;s++){ wv[s] = __expf(lg[s]-m); den += wv[s]; }
  float inv = 1.f/den;
  float acc = 0.f;
  #pragma unroll
  for(int s=0;s<9;s++){
    if(nrow[s] >= 0) acc += wv[s] * __bfloat162float(V[(size_t)nrow[s]*D_ + head*DH_ + dh]);
  }
  O[cbase] = __float2bfloat16(acc*inv);
}

// ---------------- fused temporal attention: rope + export + logits + softmax + AV ----------------
// one wave per (b,hw,h); Q/K/V bf16 [b*T1+t][hw][512]
__global__ __launch_bounds__(64) void fused_tattn(
    const bf16* __restrict__ Qb, const bf16* __restrict__ Kb, const bf16* __restrict__ Vb,
    bf16* __restrict__ O, float* __restrict__ kout, float* __restrict__ vout,
    float* __restrict__ ltout, int write_lt){
  __shared__ float Qs[17][68];
  __shared__ float Ks[17][68];
  __shared__ float Ws[17][20];
  int blk = blockIdx.x;
  int h = blk & 7, hw = (blk>>3) & 255, b = blk >> 11;
  int lane = threadIdx.x;
  const size_t tstr = (size_t)HWL*D_;
  size_t base = ((size_t)(b*T1_)*HWL + hw)*D_ + h*DH_ + lane;

  float Qr[17], Kr[17], Vr[17];
  #pragma unroll
  for(int t=0;t<17;t++){
    Qr[t] = __bfloat162float(Qb[base + t*tstr]);
    Kr[t] = __bfloat162float(Kb[base + t*tstr]);
    Vr[t] = __bfloat162float(Vb[base + t*tstr]);
  }
  // RoPE (half-split): rot_i = -x[i+32] for i<32, x[i-32] else
  int i = lane & 31;
  float freq = __expf(-9.210340372f * (float)i * (1.f/32.f));
  #pragma unroll
  for(int t=0;t<17;t++){
    float sn, cs; __sincosf((float)t * freq, &sn, &cs);
    float p = __shfl_xor(Qr[t], 32);
    float rot = (lane < 32) ? -p : p;
    Qr[t] = Qr[t]*cs + rot*sn;
    p = __shfl_xor(Kr[t], 32);
    rot = (lane < 32) ? -p : p;
    Kr[t] = Kr[t]*cs + rot*sn;
    Qs[t][lane] = Qr[t];
    Ks[t][lane] = Kr[t];
  }
  // exports (frames 0..15, fp32)
  size_t ebase = (((size_t)(b*HWL + hw)*NHH + h)*16)*64 + lane;
  #pragma unroll
  for(int t=0;t<16;t++){
    kout[ebase + t*64] = Kr[t];
    vout[ebase + t*64] = Vr[t];
  }
  __syncthreads();
  // logits: 289 (t,u) pairs over 5 iterations
  size_t lbase = (((size_t)(b*HWL + hw)*NHH + h)*T1_)*T1_;
  #pragma unroll
  for(int it=0;it<5;it++){
    int p = it*64 + lane;
    if(p < 289){
      int t = p / 17, u = p - t*17;
      float d = 0.f;
      #pragma unroll
      for(int j=0;j<16;j++){
        float4 q4 = *reinterpret_cast<const float4*>(&Qs[t][j*4]);
        float4 k4 = *reinterpret_cast<const float4*>(&Ks[u][j*4]);
        d += q4.x*k4.x + q4.y*k4.y + q4.z*k4.z + q4.w*k4.w;
      }
      bool masked = (u > t) || (t == 16 && u == 16);
      float lg = masked ? NEGV : d*0.125f;
      Ws[t][u] = lg;
      if(write_lt) ltout[lbase + t*17 + u] = lg;
    }
  }
  __syncthreads();
  // per-row softmax (17 lanes)
  if(lane < 17){
    float m = -1e30f;
    #pragma unroll
    for(int u=0;u<17;u++) m = fmaxf(m, Ws[lane][u]);
    float den = 0.f; float e[17];
    #pragma unroll
    for(int u=0;u<17;u++){ e[u] = __expf(Ws[lane][u]-m); den += e[u]; }
    float inv = 1.f/den;
    #pragma unroll
    for(int u=0;u<17;u++) Ws[lane][u] = e[u]*inv;
  }
  __syncthreads();
  // AV: O[t][lane] = sum_u W[t][u]*V[u][lane]
  #pragma unroll
  for(int t=0;t<17;t++){
    float acc = 0.f;
    #pragma unroll
    for(int u=0;u<17;u++) acc += Ws[t][u]*Vr[u];
    O[base + t*tstr] = __float2bfloat16(acc);
  }
}

// ---------------- frame-0 spatial mean broadcast ----------------
__global__ __launch_bounds__(256) void avg_frame0_kernel(float* __restrict__ X){
  int d = blockIdx.x & 511; int bb = blockIdx.x >> 9;
  int hw = threadIdx.x;
  __shared__ float sm[256];
  size_t idx = ((size_t)(bb*T1_)*HWL + hw)*D_ + d;
  sm[hw] = X[idx];
  __syncthreads();
  for(int o=128;o>0;o>>=1){ if(hw<o) sm[hw] += sm[hw+o]; __syncthreads(); }
  X[idx] = sm[0]*(1.f/256.f);
}

extern "C" void kernel_launch(void* const* d_in, const int* in_sizes, int n_in,
                              void* d_out, int out_size, void* d_ws, size_t ws_size,
                              hipStream_t stream){
  const int*   codes = (const int*)  d_in[0];
  const float* emb   = (const float*)d_in[1];
  const float* cls   = (const float*)d_in[2];
  const float* hpos  = (const float*)d_in[3];
  const float* wpos  = (const float*)d_in[4];
  const float* eng   = (const float*)d_in[5];
  const float* enb   = (const float*)d_in[6];
  const float* sn_g  = (const float*)d_in[7];
  const float* sn_b  = (const float*)d_in[8];
  const float* s_wq  = (const float*)d_in[9];
  const float* s_bq  = (const float*)d_in[10];
  const float* s_wk  = (const float*)d_in[11];
  const float* s_bk  = (const float*)d_in[12];
  const float* s_wv  = (const float*)d_in[13];
  const float* s_bv  = (const float*)d_in[14];
  const float* s_wo  = (const float*)d_in[15];
  const float* s_bo  = (const float*)d_in[16];
  const float* tn_g  = (const float*)d_in[17];
  const float* tn_b  = (const float*)d_in[18];
  const float* t_wq  = (const float*)d_in[19];
  const float* t_bq  = (const float*)d_in[20];
  const float* t_wk  = (const float*)d_in[21];
  const float* t_bk  = (const float*)d_in[22];
  const float* t_wv  = (const float*)d_in[23];
  const float* t_bv  = (const float*)d_in[24];
  const float* t_wo  = (const float*)d_in[25];
  const float* t_bo  = (const float*)d_in[26];
  const float* mn_g  = (const float*)d_in[27];
  const float* mn_b  = (const float*)d_in[28];
  const float* mw1   = (const float*)d_in[29];
  const float* mb1   = (const float*)d_in[30];
  const float* mw2   = (const float*)d_in[31];
  const float* mb2   = (const float*)d_in[32];
  const float* fn_g  = (const float*)d_in[33];
  const float* fn_b  = (const float*)d_in[34];

  float* ws = (float*)d_ws;
  const size_t NX = 4456448;               // B*T1*HW*D
  float* X   = ws;                         // fp32 [RT][512]
  bf16*  XNb = (bf16*)(X + NX);            // bf16 [RT][512]
  bf16*  Qb  = (bf16*)((float*)XNb + NX/2);
  bf16*  Kb  = (bf16*)((float*)Qb  + NX/2);
  bf16*  Vb  = (bf16*)((float*)Kb  + NX/2);
  bf16*  Wt  = (bf16*)((float*)Vb  + NX/2); // 3,145,728 bf16
  bf16*  HIDb= Qb;                          // [8704][1024] bf16, aliases Qb+Kb

  float* out0 = (float*)d_out;
  float* out1 = out0 + NX;
  float* out2 = out1 + 1183744;
  float* out3 = out2 + 25165824;

  const int RS = B__*T_*HWL;           // 8192
  const int RT = B__*T1_*HWL;          // 8704
  dim3 gQs(12, 64);                    // spatial fused QKV
  dim3 gQt(12, 68);                    // temporal fused QKV
  dim3 gOs(4, 64);                     // spatial O-proj
  dim3 gOt(4, 68);                     // temporal O-proj / MLP2
  dim3 gM1(8, 68);                     // MLP1
  dim3 wcg(32, 32, 10);

  embed_ln_kernel<<<RT/4, 256, 0, stream>>>(codes, emb, cls, hpos, wpos, eng, enb, X);

  for(int i=0;i<6;i++){
    const size_t wo = (size_t)i*D_*D_;
    wconv_kernel<<<wcg,256,0,stream>>>(s_wq+wo, s_wk+wo, s_wv+wo, s_wo+wo,
                                       t_wq+wo, t_wk+wo, t_wv+wo, t_wo+wo,
                                       mw1+(size_t)i*524288, mw2+(size_t)i*524288, Wt);
    // ---- spatial windowed attention ----
    ln_bf_kernel<<<RS/4,256,0,stream>>>(X, XNb, sn_g+i*D_, sn_b+i*D_, T_*HWL, T1_*HWL);
    gemm_qkv<<<gQs,256,0,stream>>>(XNb, Wt, s_bq+i*D_, s_bk+i*D_, s_bv+i*D_, Qb, Kb, Vb);
    spatial_attn_kernel<<<RS,512,0,stream>>>(Qb, Kb, Vb, XNb);
    gemm_mfma<0,true,false><<<gOs,256,0,stream>>>(XNb, Wt+3*262144, s_bo+i*D_, X, X, 512, 512, T_*HWL, T1_*HWL);
    // ---- temporal RoPE causal attention (fused) ----
    ln_bf_kernel<<<RT/4,256,0,stream>>>(X, XNb, tn_g+i*D_, tn_b+i*D_, T1_*HWL, T1_*HWL);
    gemm_qkv<<<gQt,256,0,stream>>>(XNb, Wt+4*262144, t_bq+i*D_, t_bk+i*D_, t_bv+i*D_, Qb, Kb, Vb);
    fused_tattn<<<4096,64,0,stream>>>(Qb, Kb, Vb, XNb,
                                      out2+(size_t)i*4194304, out3+(size_t)i*4194304,
                                      out1, (i==5)?1:0);
    gemm_mfma<0,true,false><<<gOt,256,0,stream>>>(XNb, Wt+7*262144, t_bo+i*D_, X, X, 512, 512, RT, RT);
    avg_frame0_kernel<<<1024,256,0,stream>>>(X);
    // ---- MLP ----
    ln_bf_kernel<<<RT/4,256,0,stream>>>(X, XNb, mn_g+i*D_, mn_b+i*D_, T1_*HWL, T1_*HWL);
    gemm_mfma<1,false,true ><<<gM1,256,0,stream>>>(XNb, Wt+2097152, mb1+i*1024, HIDb, nullptr, 512, 1024, RT, RT);
    gemm_mfma<0,true,false><<<gOt,256,0,stream>>>(HIDb, Wt+2621440, mb2+i*D_, X, X, 1024, 512, RT, RT);
  }
  ln_kernel<<<RT/4,256,0,stream>>>(X, out0, fn_g, fn_b, T1_*HWL, T1_*HWL);
}

// Round 4
// 1448.956 us; speedup vs baseline: 4.3226x; 1.1249x over previous
//
#include <hip/hip_runtime.h>
#include <hip/hip_bf16.h>
#include <math.h>

#define D_    512
#define NHH   8
#define DH_   64
#define T_    16
#define T1_   17
#define HWL   256
#define B__   2
#define NEGV  -1e9f

typedef __attribute__((ext_vector_type(8))) short short8;
typedef __attribute__((ext_vector_type(4))) short short4v;
typedef __attribute__((ext_vector_type(4))) float f32x4;
typedef __hip_bfloat16 bf16;

__device__ inline float wave_sum(float v){
  #pragma unroll
  for(int o=32;o>0;o>>=1) v += __shfl_xor(v,o,64);
  return v;
}
__device__ inline float b2f(unsigned short s){
  unsigned u = ((unsigned)s)<<16; float f; __builtin_memcpy(&f,&u,4); return f;
}
__device__ inline short f2bs(float f){
  bf16 h = __float2bfloat16(f); short s; __builtin_memcpy(&s,&h,2); return s;
}
__device__ inline void gload_lds16(const void* g, void* l){
  __builtin_amdgcn_global_load_lds((const __attribute__((address_space(1))) void*)g,
                                   (__attribute__((address_space(3))) void*)l, 16, 0, 0);
}

// ---------------- embedding + LN ----------------
__global__ __launch_bounds__(256) void embed_ln_kernel(
    const int* __restrict__ codes, const float* __restrict__ emb,
    const float* __restrict__ cls, const float* __restrict__ hpos,
    const float* __restrict__ wpos, const float* __restrict__ g,
    const float* __restrict__ bta, float* __restrict__ X){
  int row  = blockIdx.x*4 + (threadIdx.x>>6);
  int lane = threadIdx.x & 63;
  int hw = row % HWL; int bt = row / HWL; int t = bt % T1_; int bb = bt / T1_;
  float v[8];
  if(t < T_){
    int code = codes[(bb*T_ + t)*HWL + hw];
    const float* ep = emb  + (size_t)code*D_;
    const float* hp = hpos + (size_t)(hw & 15)*D_;
    const float* wp = wpos + (size_t)(hw >> 4)*D_;
    #pragma unroll
    for(int j=0;j<8;j++){ int d = lane + j*64; v[j] = ep[d] + hp[d] + wp[d]; }
  } else {
    #pragma unroll
    for(int j=0;j<8;j++) v[j] = cls[lane + j*64];
  }
  float s=0;
  #pragma unroll
  for(int j=0;j<8;j++) s += v[j];
  s = wave_sum(s);
  float mean = s*(1.f/512.f);
  float s2=0;
  #pragma unroll
  for(int j=0;j<8;j++){ float d0=v[j]-mean; s2 += d0*d0; }
  s2 = wave_sum(s2);
  float inv = rsqrtf(s2*(1.f/512.f) + 1e-5f);
  float* o = X + (size_t)row*D_;
  #pragma unroll
  for(int j=0;j<8;j++){ int d = lane + j*64; o[d] = (v[j]-mean)*inv*g[d] + bta[d]; }
}

// ---------------- LayerNorm, fp32 out (final), float4 vectorized ----------------
__global__ __launch_bounds__(256) void ln_kernel(
    const float* __restrict__ in, float* __restrict__ out,
    const float* __restrict__ g, const float* __restrict__ bta,
    int c_rpb, int s_rpb){
  int row  = blockIdx.x*4 + (threadIdx.x>>6);
  int lane = threadIdx.x & 63;
  int bb = row / c_rpb; int rem = row - bb*c_rpb;
  const float4* p = (const float4*)(in + ((size_t)bb*s_rpb + rem)*D_);
  float4 a = p[lane], c = p[lane+64];
  float s = a.x+a.y+a.z+a.w + c.x+c.y+c.z+c.w;
  s = wave_sum(s);
  float mean = s*(1.f/512.f);
  float s2 = (a.x-mean)*(a.x-mean)+(a.y-mean)*(a.y-mean)+(a.z-mean)*(a.z-mean)+(a.w-mean)*(a.w-mean)
           + (c.x-mean)*(c.x-mean)+(c.y-mean)*(c.y-mean)+(c.z-mean)*(c.z-mean)+(c.w-mean)*(c.w-mean);
  s2 = wave_sum(s2);
  float inv = rsqrtf(s2*(1.f/512.f) + 1e-5f);
  const float4* g4 = (const float4*)g; const float4* b4 = (const float4*)bta;
  float4 gv=g4[lane], gw=g4[lane+64], bv=b4[lane], bw=b4[lane+64];
  float4 o0 = { (a.x-mean)*inv*gv.x+bv.x, (a.y-mean)*inv*gv.y+bv.y,
                (a.z-mean)*inv*gv.z+bv.z, (a.w-mean)*inv*gv.w+bv.w };
  float4 o1 = { (c.x-mean)*inv*gw.x+bw.x, (c.y-mean)*inv*gw.y+bw.y,
                (c.z-mean)*inv*gw.z+bw.z, (c.w-mean)*inv*gw.w+bw.w };
  float4* o = (float4*)(out + (size_t)row*D_);
  o[lane] = o0; o[lane+64] = o1;
}

// ---------------- LayerNorm, bf16 out, vectorized ----------------
__global__ __launch_bounds__(256) void ln_bf_kernel(
    const float* __restrict__ in, bf16* __restrict__ out,
    const float* __restrict__ g, const float* __restrict__ bta,
    int c_rpb, int s_rpb){
  int row  = blockIdx.x*4 + (threadIdx.x>>6);
  int lane = threadIdx.x & 63;
  int bb = row / c_rpb; int rem = row - bb*c_rpb;
  const float4* p = (const float4*)(in + ((size_t)bb*s_rpb + rem)*D_);
  float4 a = p[lane], c = p[lane+64];
  float s = a.x+a.y+a.z+a.w + c.x+c.y+c.z+c.w;
  s = wave_sum(s);
  float mean = s*(1.f/512.f);
  float s2 = (a.x-mean)*(a.x-mean)+(a.y-mean)*(a.y-mean)+(a.z-mean)*(a.z-mean)+(a.w-mean)*(a.w-mean)
           + (c.x-mean)*(c.x-mean)+(c.y-mean)*(c.y-mean)+(c.z-mean)*(c.z-mean)+(c.w-mean)*(c.w-mean);
  s2 = wave_sum(s2);
  float inv = rsqrtf(s2*(1.f/512.f) + 1e-5f);
  const float4* g4 = (const float4*)g; const float4* b4 = (const float4*)bta;
  float4 gv=g4[lane], gw=g4[lane+64], bv=b4[lane], bw=b4[lane+64];
  short4v r0 = { f2bs((a.x-mean)*inv*gv.x+bv.x), f2bs((a.y-mean)*inv*gv.y+bv.y),
                 f2bs((a.z-mean)*inv*gv.z+bv.z), f2bs((a.w-mean)*inv*gv.w+bv.w) };
  short4v r1 = { f2bs((c.x-mean)*inv*gw.x+bw.x), f2bs((c.y-mean)*inv*gw.y+bw.y),
                 f2bs((c.z-mean)*inv*gw.z+bw.z), f2bs((c.w-mean)*inv*gw.w+bw.w) };
  bf16* o = out + (size_t)row*D_;
  *(short4v*)&o[lane*4]       = r0;
  *(short4v*)&o[256 + lane*4] = r1;
}

// ---------------- weight fp32[K][N] -> bf16[N][K], ALL layers at once ----------------
__global__ __launch_bounds__(256) void wconv_kernel(
    const float* sq, const float* sk, const float* sv, const float* so,
    const float* tq, const float* tk, const float* tv, const float* to,
    const float* w1, const float* w2, bf16* __restrict__ dst){
  __shared__ float sm[32][33];
  int z = blockIdx.z; int i = z/10, id = z - i*10;
  const size_t wo = (size_t)i*262144, mo = (size_t)i*524288;
  bf16* db = dst + (size_t)i*3145728;
  const float* src; bf16* d; int K, N;
  switch(id){
    case 0: src=sq+wo; d=db+0*262144;  K=512;  N=512;  break;
    case 1: src=sk+wo; d=db+1*262144;  K=512;  N=512;  break;
    case 2: src=sv+wo; d=db+2*262144;  K=512;  N=512;  break;
    case 3: src=so+wo; d=db+3*262144;  K=512;  N=512;  break;
    case 4: src=tq+wo; d=db+4*262144;  K=512;  N=512;  break;
    case 5: src=tk+wo; d=db+5*262144;  K=512;  N=512;  break;
    case 6: src=tv+wo; d=db+6*262144;  K=512;  N=512;  break;
    case 7: src=to+wo; d=db+7*262144;  K=512;  N=512;  break;
    case 8: src=w1+mo; d=db+2097152;   K=512;  N=1024; break;
    default:src=w2+mo; d=db+2621440;   K=1024; N=512;  break;
  }
  int n0 = blockIdx.x<<5, k0 = blockIdx.y<<5;
  if(n0 >= N || k0 >= K) return;
  int tx = threadIdx.x & 31, ty = threadIdx.x >> 5;
  #pragma unroll
  for(int j=0;j<4;j++) sm[ty+j*8][tx] = src[(size_t)(k0+ty+j*8)*N + n0+tx];
  __syncthreads();
  #pragma unroll
  for(int j=0;j<4;j++) d[(size_t)(n0+ty+j*8)*K + k0+tx] = __float2bfloat16(sm[tx][ty+j*8]);
}

// ---------------- bf16 MFMA GEMM (single output) ----------------
template<int ACT, bool RES, bool OBF>
__global__ __launch_bounds__(256) void gemm_mfma(
    const bf16* __restrict__ A, const bf16* __restrict__ Wt,
    const float* __restrict__ bias, void* __restrict__ outp,
    const float* __restrict__ resid, int K, int N, int c_rpb, int o_rpb){
  __shared__ __align__(16) bf16 As[128*32];
  __shared__ __align__(16) bf16 Bs[128*32];
  const int tid  = threadIdx.x;
  const int lane = tid & 63;
  const int w    = tid >> 6;
  const int row0 = blockIdx.y << 7;
  const int col0 = blockIdx.x << 7;
  const int mb = (w>>1)*64, nb = (w&1)*64;
  const int c0 = w*64 + lane;
  const int c1 = c0 + 256;
  const size_t ga0 = (size_t)(row0 + (c0>>2))*K + ((c0&3)<<3);
  const size_t ga1 = (size_t)(row0 + (c1>>2))*K + ((c1&3)<<3);
  const size_t gb0 = (size_t)(col0 + (c0>>2))*K + ((c0&3)<<3);
  const size_t gb1 = (size_t)(col0 + (c1>>2))*K + ((c1&3)<<3);

  f32x4 acc[4][4] = {};
  for(int k0=0;k0<K;k0+=32){
    gload_lds16(A  + ga0 + k0, As + (size_t)w*512);
    gload_lds16(A  + ga1 + k0, As + (size_t)(4+w)*512);
    gload_lds16(Wt + gb0 + k0, Bs + (size_t)w*512);
    gload_lds16(Wt + gb1 + k0, Bs + (size_t)(4+w)*512);
    __syncthreads();
    const short8* Av = (const short8*)As;
    const short8* Bv = (const short8*)Bs;
    short8 af[4], bfr[4];
    #pragma unroll
    for(int mi=0;mi<4;mi++) af[mi]  = Av[(mb + mi*16 + (lane&15))*4 + (lane>>4)];
    #pragma unroll
    for(int ni=0;ni<4;ni++) bfr[ni] = Bv[(nb + ni*16 + (lane&15))*4 + (lane>>4)];
    #pragma unroll
    for(int mi=0;mi<4;mi++)
      #pragma unroll
      for(int ni=0;ni<4;ni++)
        acc[mi][ni] = __builtin_amdgcn_mfma_f32_16x16x32_bf16(af[mi], bfr[ni], acc[mi][ni], 0,0,0);
    __syncthreads();
  }
  #pragma unroll
  for(int mi=0;mi<4;mi++){
    #pragma unroll
    for(int r=0;r<4;r++){
      int row = row0 + mb + mi*16 + (lane>>4)*4 + r;
      int bb = row / c_rpb;
      size_t orow = (size_t)bb*o_rpb + (row - bb*c_rpb);
      #pragma unroll
      for(int ni=0;ni<4;ni++){
        int col = col0 + nb + ni*16 + (lane&15);
        float v = acc[mi][ni][r] + bias[col];
        if(ACT==1) v = tanhf(v);
        if(RES) v += resid[orow*(size_t)N + col];
        if(OBF) ((bf16*)outp)[orow*(size_t)N + col] = __float2bfloat16(v);
        else    ((float*)outp)[orow*(size_t)N + col] = v;
      }
    }
  }
}

// ---------------- fused QKV GEMM: N=1536, bf16 outs ----------------
__global__ __launch_bounds__(256) void gemm_qkv(
    const bf16* __restrict__ A, const bf16* __restrict__ Wt,
    const float* __restrict__ bq, const float* __restrict__ bk, const float* __restrict__ bv,
    bf16* __restrict__ Qo, bf16* __restrict__ Ko, bf16* __restrict__ Vo){
  const int K = 512;
  __shared__ __align__(16) bf16 As[128*32];
  __shared__ __align__(16) bf16 Bs[128*32];
  const int tid  = threadIdx.x;
  const int lane = tid & 63;
  const int w    = tid >> 6;
  const int row0 = blockIdx.y << 7;
  const int col0 = blockIdx.x << 7;
  const int mb = (w>>1)*64, nb = (w&1)*64;
  const int c0 = w*64 + lane;
  const int c1 = c0 + 256;
  const size_t ga0 = (size_t)(row0 + (c0>>2))*K + ((c0&3)<<3);
  const size_t ga1 = (size_t)(row0 + (c1>>2))*K + ((c1&3)<<3);
  const size_t gb0 = (size_t)(col0 + (c0>>2))*K + ((c0&3)<<3);
  const size_t gb1 = (size_t)(col0 + (c1>>2))*K + ((c1&3)<<3);

  f32x4 acc[4][4] = {};
  for(int k0=0;k0<K;k0+=32){
    gload_lds16(A  + ga0 + k0, As + (size_t)w*512);
    gload_lds16(A  + ga1 + k0, As + (size_t)(4+w)*512);
    gload_lds16(Wt + gb0 + k0, Bs + (size_t)w*512);
    gload_lds16(Wt + gb1 + k0, Bs + (size_t)(4+w)*512);
    __syncthreads();
    const short8* Av = (const short8*)As;
    const short8* Bv = (const short8*)Bs;
    short8 af[4], bfr[4];
    #pragma unroll
    for(int mi=0;mi<4;mi++) af[mi]  = Av[(mb + mi*16 + (lane&15))*4 + (lane>>4)];
    #pragma unroll
    for(int ni=0;ni<4;ni++) bfr[ni] = Bv[(nb + ni*16 + (lane&15))*4 + (lane>>4)];
    #pragma unroll
    for(int mi=0;mi<4;mi++)
      #pragma unroll
      for(int ni=0;ni<4;ni++)
        acc[mi][ni] = __builtin_amdgcn_mfma_f32_16x16x32_bf16(af[mi], bfr[ni], acc[mi][ni], 0,0,0);
    __syncthreads();
  }
  const int sel = col0 >> 9;
  bf16* outp = (sel==0) ? Qo : (sel==1 ? Ko : Vo);
  const float* bp = (sel==0) ? bq : (sel==1 ? bk : bv);
  const int cb = col0 & 511;
  #pragma unroll
  for(int mi=0;mi<4;mi++){
    #pragma unroll
    for(int r=0;r<4;r++){
      int row = row0 + mb + mi*16 + (lane>>4)*4 + r;
      #pragma unroll
      for(int ni=0;ni<4;ni++){
        int col = cb + nb + ni*16 + (lane&15);
        outp[(size_t)row*512 + col] = __float2bfloat16(acc[mi][ni][r] + bp[col]);
      }
    }
  }
}

// ---------------- spatial 3x3 windowed attention: paired bf16, 2 heads/wave ----------------
__global__ __launch_bounds__(256) void spatial_attn_kernel(
    const bf16* __restrict__ Q, const bf16* __restrict__ K,
    const bf16* __restrict__ V, bf16* __restrict__ O){
  int loc = blockIdx.x;
  int hw = loc & 255;
  int hh = hw >> 4, ww = hw & 15;
  int tid = threadIdx.x, lane = tid & 63, w = tid >> 6;
  int h = w*2 + (lane>>5);
  int j = lane & 31;
  size_t base = (size_t)loc*D_ + h*DH_ + 2*j;
  unsigned uq = *(const unsigned*)&Q[base];
  float q0 = b2f((unsigned short)uq), q1 = b2f((unsigned short)(uq>>16));
  float lg[9]; int nrow[9];
  #pragma unroll
  for(int s=0;s<9;s++){
    int a = s/3 - 1, b2_ = s%3 - 1;
    int nh = hh + a, nw = ww + b2_;
    bool ok = ((unsigned)nh < 16u) && ((unsigned)nw < 16u);
    nrow[s] = ok ? (loc - hw + (nh<<4) + nw) : -1;
    float p = 0.f;
    if(ok){
      unsigned uk = *(const unsigned*)&K[(size_t)nrow[s]*D_ + h*DH_ + 2*j];
      p = q0*b2f((unsigned short)uk) + q1*b2f((unsigned short)(uk>>16));
    }
    #pragma unroll
    for(int o=16;o>0;o>>=1) p += __shfl_xor(p, o, 64);
    lg[s] = ok ? p*0.125f : NEGV;
  }
  float m = lg[0];
  #pragma unroll
  for(int s=1;s<9;s++) m = fmaxf(m, lg[s]);
  float den = 0.f, wv[9];
  #pragma unroll
  for(int s=0;s<9;s++){ wv[s] = __expf(lg[s]-m); den += wv[s]; }
  float inv = 1.f/den;
  float a0 = 0.f, a1 = 0.f;
  #pragma unroll
  for(int s=0;s<9;s++){
    if(nrow[s] >= 0){
      unsigned uv = *(const unsigned*)&V[(size_t)nrow[s]*D_ + h*DH_ + 2*j];
      a0 += wv[s]*b2f((unsigned short)uv);
      a1 += wv[s]*b2f((unsigned short)(uv>>16));
    }
  }
  unsigned up = (unsigned)(unsigned short)f2bs(a0*inv) | ((unsigned)(unsigned short)f2bs(a1*inv) << 16);
  *(unsigned*)&O[base] = up;
}

// ---------------- fused temporal attention: block = (b,hw), 8 waves = 8 heads ----------------
__global__ __launch_bounds__(512) void fused_tattn(
    const bf16* __restrict__ Qb, const bf16* __restrict__ Kb, const bf16* __restrict__ Vb,
    bf16* __restrict__ O, float* __restrict__ kout, float* __restrict__ vout,
    float* __restrict__ ltout, int write_lt){
  __shared__ __align__(16) bf16 Qs[17*520];   // rows padded +8 -> stride 1040B (260 words, +4 banks/row)
  __shared__ __align__(16) bf16 Ks[17*520];
  __shared__ __align__(16) bf16 Vs[17*512];
  __shared__ float Ws[8][17][18];
  const int tid = threadIdx.x, w = tid>>6, lane = tid&63;
  const int hw = blockIdx.x & 255, b = blockIdx.x >> 8;
  const size_t tstr = (size_t)HWL*D_;
  const size_t rb0 = ((size_t)(b*T1_)*HWL + hw)*D_;
  // coalesced loads: wave per row, 16B/lane
  for(int t=w; t<17; t+=8){
    size_t src = rb0 + (size_t)t*tstr + lane*8;
    *(short8*)&Qs[t*520 + lane*8] = *(const short8*)&Qb[src];
    *(short8*)&Ks[t*520 + lane*8] = *(const short8*)&Kb[src];
    *(short8*)&Vs[t*512 + lane*8] = *(const short8*)&Vb[src];
  }
  __syncthreads();
  // RoPE in LDS: wave w ropes head w; lanes<32 -> Q, lanes>=32 -> K
  {
    int i = lane & 31;
    float freq = __expf(-9.210340372f * (float)i * (1.f/32.f));
    bf16* P = (lane < 32) ? Qs : Ks;
    #pragma unroll
    for(int t=0;t<17;t++){
      float sn, cs; __sincosf((float)t*freq, &sn, &cs);
      int idx = t*520 + w*64 + i;
      float x1 = __bfloat162float(P[idx]);
      float x2 = __bfloat162float(P[idx+32]);
      P[idx]    = __float2bfloat16(x1*cs - x2*sn);
      P[idx+32] = __float2bfloat16(x2*cs + x1*sn);
    }
  }
  __syncthreads();
  // exports: head w, frames 0..15, fp32
  {
    size_t eb = (((size_t)(b*HWL + hw)*NHH + w)*16)*64 + lane;
    #pragma unroll
    for(int t=0;t<16;t++){
      kout[eb + t*64] = __bfloat162float(Ks[t*520 + w*64 + lane]);
      vout[eb + t*64] = __bfloat162float(Vs[t*512 + w*64 + lane]);
    }
  }
  // logits: head w, lane-per-(t,u) pair
  size_t lb = ((size_t)(b*HWL + hw)*NHH + w)*289;
  for(int p=lane; p<289; p+=64){
    int t = p/17, u = p - t*17;
    float d = 0.f;
    #pragma unroll
    for(int jj=0;jj<8;jj++){
      short8 qq = *(short8*)&Qs[t*520 + w*64 + jj*8];
      short8 kk = *(short8*)&Ks[u*520 + w*64 + jj*8];
      #pragma unroll
      for(int e=0;e<8;e++) d += b2f((unsigned short)qq[e]) * b2f((unsigned short)kk[e]);
    }
    bool masked = (u > t) || (t == 16 && u == 16);
    float lg = masked ? NEGV : d*0.125f;
    Ws[w][t][u] = lg;
    if(write_lt) ltout[lb + t*17 + u] = lg;
  }
  __syncthreads();
  // softmax: 17 lanes of wave w handle 17 rows
  if(lane < 17){
    float m = -1e30f;
    #pragma unroll
    for(int u=0;u<17;u++) m = fmaxf(m, Ws[w][lane][u]);
    float den = 0.f, e[17];
    #pragma unroll
    for(int u=0;u<17;u++){ e[u] = __expf(Ws[w][lane][u]-m); den += e[u]; }
    float inv = 1.f/den;
    #pragma unroll
    for(int u=0;u<17;u++) Ws[w][lane][u] = e[u]*inv;
  }
  __syncthreads();
  // AV: lane = dh of head w; V preloaded to registers
  float Vr[17];
  #pragma unroll
  for(int u=0;u<17;u++) Vr[u] = __bfloat162float(Vs[u*512 + w*64 + lane]);
  #pragma unroll
  for(int t=0;t<17;t++){
    float acc = 0.f;
    #pragma unroll
    for(int u=0;u<17;u++) acc += Ws[w][t][u]*Vr[u];
    O[rb0 + (size_t)t*tstr + w*64 + lane] = __float2bfloat16(acc);
  }
}

// ---------------- frame-0 spatial mean broadcast ----------------
__global__ __launch_bounds__(256) void avg_frame0_kernel(float* __restrict__ X){
  int d = blockIdx.x & 511; int bb = blockIdx.x >> 9;
  int hw = threadIdx.x;
  __shared__ float sm[256];
  size_t idx = ((size_t)(bb*T1_)*HWL + hw)*D_ + d;
  sm[hw] = X[idx];
  __syncthreads();
  for(int o=128;o>0;o>>=1){ if(hw<o) sm[hw] += sm[hw+o]; __syncthreads(); }
  X[idx] = sm[0]*(1.f/256.f);
}

extern "C" void kernel_launch(void* const* d_in, const int* in_sizes, int n_in,
                              void* d_out, int out_size, void* d_ws, size_t ws_size,
                              hipStream_t stream){
  const int*   codes = (const int*)  d_in[0];
  const float* emb   = (const float*)d_in[1];
  const float* cls   = (const float*)d_in[2];
  const float* hpos  = (const float*)d_in[3];
  const float* wpos  = (const float*)d_in[4];
  const float* eng   = (const float*)d_in[5];
  const float* enb   = (const float*)d_in[6];
  const float* sn_g  = (const float*)d_in[7];
  const float* sn_b  = (const float*)d_in[8];
  const float* s_wq  = (const float*)d_in[9];
  const float* s_bq  = (const float*)d_in[10];
  const float* s_wk  = (const float*)d_in[11];
  const float* s_bk  = (const float*)d_in[12];
  const float* s_wv  = (const float*)d_in[13];
  const float* s_bv  = (const float*)d_in[14];
  const float* s_wo  = (const float*)d_in[15];
  const float* s_bo  = (const float*)d_in[16];
  const float* tn_g  = (const float*)d_in[17];
  const float* tn_b  = (const float*)d_in[18];
  const float* t_wq  = (const float*)d_in[19];
  const float* t_bq  = (const float*)d_in[20];
  const float* t_wk  = (const float*)d_in[21];
  const float* t_bk  = (const float*)d_in[22];
  const float* t_wv  = (const float*)d_in[23];
  const float* t_bv  = (const float*)d_in[24];
  const float* t_wo  = (const float*)d_in[25];
  const float* t_bo  = (const float*)d_in[26];
  const float* mn_g  = (const float*)d_in[27];
  const float* mn_b  = (const float*)d_in[28];
  const float* mw1   = (const float*)d_in[29];
  const float* mb1   = (const float*)d_in[30];
  const float* mw2   = (const float*)d_in[31];
  const float* mb2   = (const float*)d_in[32];
  const float* fn_g  = (const float*)d_in[33];
  const float* fn_b  = (const float*)d_in[34];

  float* ws = (float*)d_ws;
  const size_t NX = 4456448;               // B*T1*HW*D
  float* X   = ws;                         // fp32 [RT][512]
  bf16*  XNb = (bf16*)(X + NX);            // bf16 [RT][512]
  bf16*  Qb  = (bf16*)((float*)XNb + NX/2);
  bf16*  Kb  = (bf16*)((float*)Qb  + NX/2);
  bf16*  Vb  = (bf16*)((float*)Kb  + NX/2);
  bf16*  Wt  = (bf16*)((float*)Vb  + NX/2); // 6 layers x 3,145,728 bf16
  bf16*  HIDb= Qb;                          // [8704][1024] bf16, aliases Qb+Kb

  float* out0 = (float*)d_out;
  float* out1 = out0 + NX;
  float* out2 = out1 + 1183744;
  float* out3 = out2 + 25165824;

  const int RS = B__*T_*HWL;           // 8192
  const int RT = B__*T1_*HWL;          // 8704
  dim3 gQs(12, 64);
  dim3 gQt(12, 68);
  dim3 gOs(4, 64);
  dim3 gOt(4, 68);
  dim3 gM1(8, 68);
  dim3 wcg(32, 32, 60);

  embed_ln_kernel<<<RT/4, 256, 0, stream>>>(codes, emb, cls, hpos, wpos, eng, enb, X);
  wconv_kernel<<<wcg,256,0,stream>>>(s_wq, s_wk, s_wv, s_wo, t_wq, t_wk, t_wv, t_wo, mw1, mw2, Wt);

  for(int i=0;i<6;i++){
    bf16* Wl = Wt + (size_t)i*3145728;
    // ---- spatial windowed attention ----
    ln_bf_kernel<<<RS/4,256,0,stream>>>(X, XNb, sn_g+i*D_, sn_b+i*D_, T_*HWL, T1_*HWL);
    gemm_qkv<<<gQs,256,0,stream>>>(XNb, Wl, s_bq+i*D_, s_bk+i*D_, s_bv+i*D_, Qb, Kb, Vb);
    spatial_attn_kernel<<<RS,256,0,stream>>>(Qb, Kb, Vb, XNb);
    gemm_mfma<0,true,false><<<gOs,256,0,stream>>>(XNb, Wl+3*262144, s_bo+i*D_, X, X, 512, 512, T_*HWL, T1_*HWL);
    // ---- temporal RoPE causal attention (fused) ----
    ln_bf_kernel<<<RT/4,256,0,stream>>>(X, XNb, tn_g+i*D_, tn_b+i*D_, T1_*HWL, T1_*HWL);
    gemm_qkv<<<gQt,256,0,stream>>>(XNb, Wl+4*262144, t_bq+i*D_, t_bk+i*D_, t_bv+i*D_, Qb, Kb, Vb);
    fused_tattn<<<512,512,0,stream>>>(Qb, Kb, Vb, XNb,
                                      out2+(size_t)i*4194304, out3+(size_t)i*4194304,
                                      out1, (i==5)?1:0);
    gemm_mfma<0,true,false><<<gOt,256,0,stream>>>(XNb, Wl+7*262144, t_bo+i*D_, X, X, 512, 512, RT, RT);
    avg_frame0_kernel<<<1024,256,0,stream>>>(X);
    // ---- MLP ----
    ln_bf_kernel<<<RT/4,256,0,stream>>>(X, XNb, mn_g+i*D_, mn_b+i*D_, T1_*HWL, T1_*HWL);
    gemm_mfma<1,false,true ><<<gM1,256,0,stream>>>(XNb, Wl+2097152, mb1+i*1024, HIDb, nullptr, 512, 1024, RT, RT);
    gemm_mfma<0,true,false><<<gOt,256,0,stream>>>(HIDb, Wl+2621440, mb2+i*D_, X, X, 1024, 512, RT, RT);
  }
  ln_kernel<<<RT/4,256,0,stream>>>(X, out0, fn_g, fn_b, T1_*HWL, T1_*HWL);
}

// Round 5
// 1406.280 us; speedup vs baseline: 4.4537x; 1.0303x over previous
//
#include <hip/hip_runtime.h>
#include <hip/hip_bf16.h>
#include <math.h>

#define D_    512
#define NHH   8
#define DH_   64
#define T_    16
#define T1_   17
#define HWL   256
#define B__   2
#define NEGV  -1e9f

typedef __attribute__((ext_vector_type(8))) short short8;
typedef __attribute__((ext_vector_type(4))) short short4v;
typedef __attribute__((ext_vector_type(4))) float f32x4;
typedef __hip_bfloat16 bf16;

__device__ inline float wave_sum(float v){
  #pragma unroll
  for(int o=32;o>0;o>>=1) v += __shfl_xor(v,o,64);
  return v;
}
__device__ inline float b2f(unsigned short s){
  unsigned u = ((unsigned)s)<<16; float f; __builtin_memcpy(&f,&u,4); return f;
}
__device__ inline short f2bs(float f){
  bf16 h = __float2bfloat16(f); short s; __builtin_memcpy(&s,&h,2); return s;
}
__device__ inline void gload_lds16(const void* g, void* l){
  __builtin_amdgcn_global_load_lds((const __attribute__((address_space(1))) void*)g,
                                   (__attribute__((address_space(3))) void*)l, 16, 0, 0);
}

// ---------------- embedding + LN ----------------
__global__ __launch_bounds__(256) void embed_ln_kernel(
    const int* __restrict__ codes, const float* __restrict__ emb,
    const float* __restrict__ cls, const float* __restrict__ hpos,
    const float* __restrict__ wpos, const float* __restrict__ g,
    const float* __restrict__ bta, float* __restrict__ X){
  int row  = blockIdx.x*4 + (threadIdx.x>>6);
  int lane = threadIdx.x & 63;
  int hw = row % HWL; int bt = row / HWL; int t = bt % T1_; int bb = bt / T1_;
  float v[8];
  if(t < T_){
    int code = codes[(bb*T_ + t)*HWL + hw];
    const float* ep = emb  + (size_t)code*D_;
    const float* hp = hpos + (size_t)(hw & 15)*D_;
    const float* wp = wpos + (size_t)(hw >> 4)*D_;
    #pragma unroll
    for(int j=0;j<8;j++){ int d = lane + j*64; v[j] = ep[d] + hp[d] + wp[d]; }
  } else {
    #pragma unroll
    for(int j=0;j<8;j++) v[j] = cls[lane + j*64];
  }
  float s=0;
  #pragma unroll
  for(int j=0;j<8;j++) s += v[j];
  s = wave_sum(s);
  float mean = s*(1.f/512.f);
  float s2=0;
  #pragma unroll
  for(int j=0;j<8;j++){ float d0=v[j]-mean; s2 += d0*d0; }
  s2 = wave_sum(s2);
  float inv = rsqrtf(s2*(1.f/512.f) + 1e-5f);
  float* o = X + (size_t)row*D_;
  #pragma unroll
  for(int j=0;j<8;j++){ int d = lane + j*64; o[d] = (v[j]-mean)*inv*g[d] + bta[d]; }
}

// ---------------- LayerNorm, fp32 out (final), float4 vectorized ----------------
__global__ __launch_bounds__(256) void ln_kernel(
    const float* __restrict__ in, float* __restrict__ out,
    const float* __restrict__ g, const float* __restrict__ bta,
    int c_rpb, int s_rpb){
  int row  = blockIdx.x*4 + (threadIdx.x>>6);
  int lane = threadIdx.x & 63;
  int bb = row / c_rpb; int rem = row - bb*c_rpb;
  const float4* p = (const float4*)(in + ((size_t)bb*s_rpb + rem)*D_);
  float4 a = p[lane], c = p[lane+64];
  float s = a.x+a.y+a.z+a.w + c.x+c.y+c.z+c.w;
  s = wave_sum(s);
  float mean = s*(1.f/512.f);
  float s2 = (a.x-mean)*(a.x-mean)+(a.y-mean)*(a.y-mean)+(a.z-mean)*(a.z-mean)+(a.w-mean)*(a.w-mean)
           + (c.x-mean)*(c.x-mean)+(c.y-mean)*(c.y-mean)+(c.z-mean)*(c.z-mean)+(c.w-mean)*(c.w-mean);
  s2 = wave_sum(s2);
  float inv = rsqrtf(s2*(1.f/512.f) + 1e-5f);
  const float4* g4 = (const float4*)g; const float4* b4 = (const float4*)bta;
  float4 gv=g4[lane], gw=g4[lane+64], bv=b4[lane], bw=b4[lane+64];
  float4 o0 = { (a.x-mean)*inv*gv.x+bv.x, (a.y-mean)*inv*gv.y+bv.y,
                (a.z-mean)*inv*gv.z+bv.z, (a.w-mean)*inv*gv.w+bv.w };
  float4 o1 = { (c.x-mean)*inv*gw.x+bw.x, (c.y-mean)*inv*gw.y+bw.y,
                (c.z-mean)*inv*gw.z+bw.z, (c.w-mean)*inv*gw.w+bw.w };
  float4* o = (float4*)(out + (size_t)row*D_);
  o[lane] = o0; o[lane+64] = o1;
}

// ---------------- LayerNorm, bf16 out, vectorized ----------------
__global__ __launch_bounds__(256) void ln_bf_kernel(
    const float* __restrict__ in, bf16* __restrict__ out,
    const float* __restrict__ g, const float* __restrict__ bta,
    int c_rpb, int s_rpb){
  int row  = blockIdx.x*4 + (threadIdx.x>>6);
  int lane = threadIdx.x & 63;
  int bb = row / c_rpb; int rem = row - bb*c_rpb;
  const float4* p = (const float4*)(in + ((size_t)bb*s_rpb + rem)*D_);
  float4 a = p[lane], c = p[lane+64];
  float s = a.x+a.y+a.z+a.w + c.x+c.y+c.z+c.w;
  s = wave_sum(s);
  float mean = s*(1.f/512.f);
  float s2 = (a.x-mean)*(a.x-mean)+(a.y-mean)*(a.y-mean)+(a.z-mean)*(a.z-mean)+(a.w-mean)*(a.w-mean)
           + (c.x-mean)*(c.x-mean)+(c.y-mean)*(c.y-mean)+(c.z-mean)*(c.z-mean)+(c.w-mean)*(c.w-mean);
  s2 = wave_sum(s2);
  float inv = rsqrtf(s2*(1.f/512.f) + 1e-5f);
  const float4* g4 = (const float4*)g; const float4* b4 = (const float4*)bta;
  float4 gv=g4[lane], gw=g4[lane+64], bv=b4[lane], bw=b4[lane+64];
  short4v r0 = { f2bs((a.x-mean)*inv*gv.x+bv.x), f2bs((a.y-mean)*inv*gv.y+bv.y),
                 f2bs((a.z-mean)*inv*gv.z+bv.z), f2bs((a.w-mean)*inv*gv.w+bv.w) };
  short4v r1 = { f2bs((c.x-mean)*inv*gw.x+bw.x), f2bs((c.y-mean)*inv*gw.y+bw.y),
                 f2bs((c.z-mean)*inv*gw.z+bw.z), f2bs((c.w-mean)*inv*gw.w+bw.w) };
  bf16* o = out + (size_t)row*D_;
  *(short4v*)&o[lane*4]       = r0;
  *(short4v*)&o[256 + lane*4] = r1;
}

// ---------------- weight fp32[K][N] -> bf16[N][K], ALL layers at once ----------------
__global__ __launch_bounds__(256) void wconv_kernel(
    const float* sq, const float* sk, const float* sv, const float* so,
    const float* tq, const float* tk, const float* tv, const float* to,
    const float* w1, const float* w2, bf16* __restrict__ dst){
  __shared__ float sm[32][33];
  int z = blockIdx.z; int i = z/10, id = z - i*10;
  const size_t wo = (size_t)i*262144, mo = (size_t)i*524288;
  bf16* db = dst + (size_t)i*3145728;
  const float* src; bf16* d; int K, N;
  switch(id){
    case 0: src=sq+wo; d=db+0*262144;  K=512;  N=512;  break;
    case 1: src=sk+wo; d=db+1*262144;  K=512;  N=512;  break;
    case 2: src=sv+wo; d=db+2*262144;  K=512;  N=512;  break;
    case 3: src=so+wo; d=db+3*262144;  K=512;  N=512;  break;
    case 4: src=tq+wo; d=db+4*262144;  K=512;  N=512;  break;
    case 5: src=tk+wo; d=db+5*262144;  K=512;  N=512;  break;
    case 6: src=tv+wo; d=db+6*262144;  K=512;  N=512;  break;
    case 7: src=to+wo; d=db+7*262144;  K=512;  N=512;  break;
    case 8: src=w1+mo; d=db+2097152;   K=512;  N=1024; break;
    default:src=w2+mo; d=db+2621440;   K=1024; N=512;  break;
  }
  int n0 = blockIdx.x<<5, k0 = blockIdx.y<<5;
  if(n0 >= N || k0 >= K) return;
  int tx = threadIdx.x & 31, ty = threadIdx.x >> 5;
  #pragma unroll
  for(int j=0;j<4;j++) sm[ty+j*8][tx] = src[(size_t)(k0+ty+j*8)*N + n0+tx];
  __syncthreads();
  #pragma unroll
  for(int j=0;j<4;j++) d[(size_t)(n0+ty+j*8)*K + k0+tx] = __float2bfloat16(sm[tx][ty+j*8]);
}

// ---------------- bf16 MFMA GEMM, 128x128 tile ----------------
template<int ACT, bool RES, bool OBF>
__global__ __launch_bounds__(256) void gemm_mfma(
    const bf16* __restrict__ A, const bf16* __restrict__ Wt,
    const float* __restrict__ bias, void* __restrict__ outp,
    const float* __restrict__ resid, int K, int N, int c_rpb, int o_rpb){
  __shared__ __align__(16) bf16 As[128*32];
  __shared__ __align__(16) bf16 Bs[128*32];
  const int tid  = threadIdx.x;
  const int lane = tid & 63;
  const int w    = tid >> 6;
  const int row0 = blockIdx.y << 7;
  const int col0 = blockIdx.x << 7;
  const int mb = (w>>1)*64, nb = (w&1)*64;
  const int c0 = w*64 + lane;
  const int c1 = c0 + 256;
  const size_t ga0 = (size_t)(row0 + (c0>>2))*K + ((c0&3)<<3);
  const size_t ga1 = (size_t)(row0 + (c1>>2))*K + ((c1&3)<<3);
  const size_t gb0 = (size_t)(col0 + (c0>>2))*K + ((c0&3)<<3);
  const size_t gb1 = (size_t)(col0 + (c1>>2))*K + ((c1&3)<<3);

  f32x4 acc[4][4] = {};
  for(int k0=0;k0<K;k0+=32){
    gload_lds16(A  + ga0 + k0, As + (size_t)w*512);
    gload_lds16(A  + ga1 + k0, As + (size_t)(4+w)*512);
    gload_lds16(Wt + gb0 + k0, Bs + (size_t)w*512);
    gload_lds16(Wt + gb1 + k0, Bs + (size_t)(4+w)*512);
    __syncthreads();
    const short8* Av = (const short8*)As;
    const short8* Bv = (const short8*)Bs;
    short8 af[4], bfr[4];
    #pragma unroll
    for(int mi=0;mi<4;mi++) af[mi]  = Av[(mb + mi*16 + (lane&15))*4 + (lane>>4)];
    #pragma unroll
    for(int ni=0;ni<4;ni++) bfr[ni] = Bv[(nb + ni*16 + (lane&15))*4 + (lane>>4)];
    #pragma unroll
    for(int mi=0;mi<4;mi++)
      #pragma unroll
      for(int ni=0;ni<4;ni++)
        acc[mi][ni] = __builtin_amdgcn_mfma_f32_16x16x32_bf16(af[mi], bfr[ni], acc[mi][ni], 0,0,0);
    __syncthreads();
  }
  #pragma unroll
  for(int mi=0;mi<4;mi++){
    #pragma unroll
    for(int r=0;r<4;r++){
      int row = row0 + mb + mi*16 + (lane>>4)*4 + r;
      int bb = row / c_rpb;
      size_t orow = (size_t)bb*o_rpb + (row - bb*c_rpb);
      #pragma unroll
      for(int ni=0;ni<4;ni++){
        int col = col0 + nb + ni*16 + (lane&15);
        float v = acc[mi][ni][r] + bias[col];
        if(ACT==1) v = tanhf(v);
        if(RES) v += resid[orow*(size_t)N + col];
        if(OBF) ((bf16*)outp)[orow*(size_t)N + col] = __float2bfloat16(v);
        else    ((float*)outp)[orow*(size_t)N + col] = v;
      }
    }
  }
}

// ---------------- bf16 MFMA GEMM, 64x64 tile (for skinny N=512 GEMMs: 4+ blocks/CU) ----------------
template<int ACT, bool RES, bool OBF>
__global__ __launch_bounds__(256) void gemm_mfma64(
    const bf16* __restrict__ A, const bf16* __restrict__ Wt,
    const float* __restrict__ bias, void* __restrict__ outp,
    const float* __restrict__ resid, int K, int N, int c_rpb, int o_rpb){
  __shared__ __align__(16) bf16 As[64*32];
  __shared__ __align__(16) bf16 Bs[64*32];
  const int tid  = threadIdx.x;
  const int lane = tid & 63;
  const int w    = tid >> 6;
  const int row0 = blockIdx.y << 6;
  const int col0 = blockIdx.x << 6;
  const int mw = (w>>1)*32, nw = (w&1)*32;
  // 256 chunks of 16B per 64x32 tile; chunk c -> row c>>2, kofs (c&3)*8
  const size_t ga = (size_t)(row0 + (tid>>2))*K + ((tid&3)<<3);
  const size_t gb = (size_t)(col0 + (tid>>2))*K + ((tid&3)<<3);

  f32x4 acc[2][2] = {};
  for(int k0=0;k0<K;k0+=32){
    gload_lds16(A  + ga + k0, As + (size_t)w*512);
    gload_lds16(Wt + gb + k0, Bs + (size_t)w*512);
    __syncthreads();
    const short8* Av = (const short8*)As;
    const short8* Bv = (const short8*)Bs;
    short8 af[2], bfr[2];
    #pragma unroll
    for(int mi=0;mi<2;mi++) af[mi]  = Av[(mw + mi*16 + (lane&15))*4 + (lane>>4)];
    #pragma unroll
    for(int ni=0;ni<2;ni++) bfr[ni] = Bv[(nw + ni*16 + (lane&15))*4 + (lane>>4)];
    #pragma unroll
    for(int mi=0;mi<2;mi++)
      #pragma unroll
      for(int ni=0;ni<2;ni++)
        acc[mi][ni] = __builtin_amdgcn_mfma_f32_16x16x32_bf16(af[mi], bfr[ni], acc[mi][ni], 0,0,0);
    __syncthreads();
  }
  #pragma unroll
  for(int mi=0;mi<2;mi++){
    #pragma unroll
    for(int r=0;r<4;r++){
      int row = row0 + mw + mi*16 + (lane>>4)*4 + r;
      int bb = row / c_rpb;
      size_t orow = (size_t)bb*o_rpb + (row - bb*c_rpb);
      #pragma unroll
      for(int ni=0;ni<2;ni++){
        int col = col0 + nw + ni*16 + (lane&15);
        float v = acc[mi][ni][r] + bias[col];
        if(ACT==1) v = tanhf(v);
        if(RES) v += resid[orow*(size_t)N + col];
        if(OBF) ((bf16*)outp)[orow*(size_t)N + col] = __float2bfloat16(v);
        else    ((float*)outp)[orow*(size_t)N + col] = v;
      }
    }
  }
}

// ---------------- fused QKV GEMM: N=1536, bf16 outs ----------------
__global__ __launch_bounds__(256) void gemm_qkv(
    const bf16* __restrict__ A, const bf16* __restrict__ Wt,
    const float* __restrict__ bq, const float* __restrict__ bk, const float* __restrict__ bv,
    bf16* __restrict__ Qo, bf16* __restrict__ Ko, bf16* __restrict__ Vo){
  const int K = 512;
  __shared__ __align__(16) bf16 As[128*32];
  __shared__ __align__(16) bf16 Bs[128*32];
  const int tid  = threadIdx.x;
  const int lane = tid & 63;
  const int w    = tid >> 6;
  const int row0 = blockIdx.y << 7;
  const int col0 = blockIdx.x << 7;
  const int mb = (w>>1)*64, nb = (w&1)*64;
  const int c0 = w*64 + lane;
  const int c1 = c0 + 256;
  const size_t ga0 = (size_t)(row0 + (c0>>2))*K + ((c0&3)<<3);
  const size_t ga1 = (size_t)(row0 + (c1>>2))*K + ((c1&3)<<3);
  const size_t gb0 = (size_t)(col0 + (c0>>2))*K + ((c0&3)<<3);
  const size_t gb1 = (size_t)(col0 + (c1>>2))*K + ((c1&3)<<3);

  f32x4 acc[4][4] = {};
  for(int k0=0;k0<K;k0+=32){
    gload_lds16(A  + ga0 + k0, As + (size_t)w*512);
    gload_lds16(A  + ga1 + k0, As + (size_t)(4+w)*512);
    gload_lds16(Wt + gb0 + k0, Bs + (size_t)w*512);
    gload_lds16(Wt + gb1 + k0, Bs + (size_t)(4+w)*512);
    __syncthreads();
    const short8* Av = (const short8*)As;
    const short8* Bv = (const short8*)Bs;
    short8 af[4], bfr[4];
    #pragma unroll
    for(int mi=0;mi<4;mi++) af[mi]  = Av[(mb + mi*16 + (lane&15))*4 + (lane>>4)];
    #pragma unroll
    for(int ni=0;ni<4;ni++) bfr[ni] = Bv[(nb + ni*16 + (lane&15))*4 + (lane>>4)];
    #pragma unroll
    for(int mi=0;mi<4;mi++)
      #pragma unroll
      for(int ni=0;ni<4;ni++)
        acc[mi][ni] = __builtin_amdgcn_mfma_f32_16x16x32_bf16(af[mi], bfr[ni], acc[mi][ni], 0,0,0);
    __syncthreads();
  }
  const int sel = col0 >> 9;
  bf16* outp = (sel==0) ? Qo : (sel==1 ? Ko : Vo);
  const float* bp = (sel==0) ? bq : (sel==1 ? bk : bv);
  const int cb = col0 & 511;
  #pragma unroll
  for(int mi=0;mi<4;mi++){
    #pragma unroll
    for(int r=0;r<4;r++){
      int row = row0 + mb + mi*16 + (lane>>4)*4 + r;
      #pragma unroll
      for(int ni=0;ni<4;ni++){
        int col = cb + nb + ni*16 + (lane&15);
        outp[(size_t)row*512 + col] = __float2bfloat16(acc[mi][ni][r] + bp[col]);
      }
    }
  }
}

// ---------------- spatial 3x3 windowed attention: paired bf16, 2 heads/wave ----------------
__global__ __launch_bounds__(256) void spatial_attn_kernel(
    const bf16* __restrict__ Q, const bf16* __restrict__ K,
    const bf16* __restrict__ V, bf16* __restrict__ O){
  int loc = blockIdx.x;
  int hw = loc & 255;
  int hh = hw >> 4, ww = hw & 15;
  int tid = threadIdx.x, lane = tid & 63, w = tid >> 6;
  int h = w*2 + (lane>>5);
  int j = lane & 31;
  size_t base = (size_t)loc*D_ + h*DH_ + 2*j;
  unsigned uq = *(const unsigned*)&Q[base];
  float q0 = b2f((unsigned short)uq), q1 = b2f((unsigned short)(uq>>16));
  float lg[9]; int nrow[9];
  #pragma unroll
  for(int s=0;s<9;s++){
    int a = s/3 - 1, b2_ = s%3 - 1;
    int nh = hh + a, nw = ww + b2_;
    bool ok = ((unsigned)nh < 16u) && ((unsigned)nw < 16u);
    nrow[s] = ok ? (loc - hw + (nh<<4) + nw) : -1;
    float p = 0.f;
    if(ok){
      unsigned uk = *(const unsigned*)&K[(size_t)nrow[s]*D_ + h*DH_ + 2*j];
      p = q0*b2f((unsigned short)uk) + q1*b2f((unsigned short)(uk>>16));
    }
    #pragma unroll
    for(int o=16;o>0;o>>=1) p += __shfl_xor(p, o, 64);
    lg[s] = ok ? p*0.125f : NEGV;
  }
  float m = lg[0];
  #pragma unroll
  for(int s=1;s<9;s++) m = fmaxf(m, lg[s]);
  float den = 0.f, wv[9];
  #pragma unroll
  for(int s=0;s<9;s++){ wv[s] = __expf(lg[s]-m); den += wv[s]; }
  float inv = 1.f/den;
  float a0 = 0.f, a1 = 0.f;
  #pragma unroll
  for(int s=0;s<9;s++){
    if(nrow[s] >= 0){
      unsigned uv = *(const unsigned*)&V[(size_t)nrow[s]*D_ + h*DH_ + 2*j];
      a0 += wv[s]*b2f((unsigned short)uv);
      a1 += wv[s]*b2f((unsigned short)(uv>>16));
    }
  }
  unsigned up = (unsigned)(unsigned short)f2bs(a0*inv) | ((unsigned)(unsigned short)f2bs(a1*inv) << 16);
  *(unsigned*)&O[base] = up;
}

// ---------------- fused temporal attention: block = (b,hw), 8 waves = 8 heads ----------------
__global__ __launch_bounds__(512) void fused_tattn(
    const bf16* __restrict__ Qb, const bf16* __restrict__ Kb, const bf16* __restrict__ Vb,
    bf16* __restrict__ O, float* __restrict__ kout, float* __restrict__ vout,
    float* __restrict__ ltout, int write_lt){
  __shared__ __align__(16) bf16 Qs[17*520];
  __shared__ __align__(16) bf16 Ks[17*520];
  __shared__ __align__(16) bf16 Vs[17*512];
  __shared__ float Ws[8][17][18];
  const int tid = threadIdx.x, w = tid>>6, lane = tid&63;
  const int hw = blockIdx.x & 255, b = blockIdx.x >> 8;
  const size_t tstr = (size_t)HWL*D_;
  const size_t rb0 = ((size_t)(b*T1_)*HWL + hw)*D_;
  for(int t=w; t<17; t+=8){
    size_t src = rb0 + (size_t)t*tstr + lane*8;
    *(short8*)&Qs[t*520 + lane*8] = *(const short8*)&Qb[src];
    *(short8*)&Ks[t*520 + lane*8] = *(const short8*)&Kb[src];
    *(short8*)&Vs[t*512 + lane*8] = *(const short8*)&Vb[src];
  }
  __syncthreads();
  {
    int i = lane & 31;
    float freq = __expf(-9.210340372f * (float)i * (1.f/32.f));
    bf16* P = (lane < 32) ? Qs : Ks;
    #pragma unroll
    for(int t=0;t<17;t++){
      float sn, cs; __sincosf((float)t*freq, &sn, &cs);
      int idx = t*520 + w*64 + i;
      float x1 = __bfloat162float(P[idx]);
      float x2 = __bfloat162float(P[idx+32]);
      P[idx]    = __float2bfloat16(x1*cs - x2*sn);
      P[idx+32] = __float2bfloat16(x2*cs + x1*sn);
    }
  }
  __syncthreads();
  {
    size_t eb = (((size_t)(b*HWL + hw)*NHH + w)*16)*64 + lane;
    #pragma unroll
    for(int t=0;t<16;t++){
      kout[eb + t*64] = __bfloat162float(Ks[t*520 + w*64 + lane]);
      vout[eb + t*64] = __bfloat162float(Vs[t*512 + w*64 + lane]);
    }
  }
  size_t lb = ((size_t)(b*HWL + hw)*NHH + w)*289;
  for(int p=lane; p<289; p+=64){
    int t = p/17, u = p - t*17;
    float d = 0.f;
    #pragma unroll
    for(int jj=0;jj<8;jj++){
      short8 qq = *(short8*)&Qs[t*520 + w*64 + jj*8];
      short8 kk = *(short8*)&Ks[u*520 + w*64 + jj*8];
      #pragma unroll
      for(int e=0;e<8;e++) d += b2f((unsigned short)qq[e]) * b2f((unsigned short)kk[e]);
    }
    bool masked = (u > t) || (t == 16 && u == 16);
    float lg = masked ? NEGV : d*0.125f;
    Ws[w][t][u] = lg;
    if(write_lt) ltout[lb + t*17 + u] = lg;
  }
  __syncthreads();
  if(lane < 17){
    float m = -1e30f;
    #pragma unroll
    for(int u=0;u<17;u++) m = fmaxf(m, Ws[w][lane][u]);
    float den = 0.f, e[17];
    #pragma unroll
    for(int u=0;u<17;u++){ e[u] = __expf(Ws[w][lane][u]-m); den += e[u]; }
    float inv = 1.f/den;
    #pragma unroll
    for(int u=0;u<17;u++) Ws[w][lane][u] = e[u]*inv;
  }
  __syncthreads();
  float Vr[17];
  #pragma unroll
  for(int u=0;u<17;u++) Vr[u] = __bfloat162float(Vs[u*512 + w*64 + lane]);
  #pragma unroll
  for(int t=0;t<17;t++){
    float acc = 0.f;
    #pragma unroll
    for(int u=0;u<17;u++) acc += Ws[w][t][u]*Vr[u];
    O[rb0 + (size_t)t*tstr + w*64 + lane] = __float2bfloat16(acc);
  }
}

// ---------------- frame-0 spatial mean broadcast ----------------
__global__ __launch_bounds__(256) void avg_frame0_kernel(float* __restrict__ X){
  int d = blockIdx.x & 511; int bb = blockIdx.x >> 9;
  int hw = threadIdx.x;
  __shared__ float sm[256];
  size_t idx = ((size_t)(bb*T1_)*HWL + hw)*D_ + d;
  sm[hw] = X[idx];
  __syncthreads();
  for(int o=128;o>0;o>>=1){ if(hw<o) sm[hw] += sm[hw+o]; __syncthreads(); }
  X[idx] = sm[0]*(1.f/256.f);
}

extern "C" void kernel_launch(void* const* d_in, const int* in_sizes, int n_in,
                              void* d_out, int out_size, void* d_ws, size_t ws_size,
                              hipStream_t stream){
  const int*   codes = (const int*)  d_in[0];
  const float* emb   = (const float*)d_in[1];
  const float* cls   = (const float*)d_in[2];
  const float* hpos  = (const float*)d_in[3];
  const float* wpos  = (const float*)d_in[4];
  const float* eng   = (const float*)d_in[5];
  const float* enb   = (const float*)d_in[6];
  const float* sn_g  = (const float*)d_in[7];
  const float* sn_b  = (const float*)d_in[8];
  const float* s_wq  = (const float*)d_in[9];
  const float* s_bq  = (const float*)d_in[10];
  const float* s_wk  = (const float*)d_in[11];
  const float* s_bk  = (const float*)d_in[12];
  const float* s_wv  = (const float*)d_in[13];
  const float* s_bv  = (const float*)d_in[14];
  const float* s_wo  = (const float*)d_in[15];
  const float* s_bo  = (const float*)d_in[16];
  const float* tn_g  = (const float*)d_in[17];
  const float* tn_b  = (const float*)d_in[18];
  const float* t_wq  = (const float*)d_in[19];
  const float* t_bq  = (const float*)d_in[20];
  const float* t_wk  = (const float*)d_in[21];
  const float* t_bk  = (const float*)d_in[22];
  const float* t_wv  = (const float*)d_in[23];
  const float* t_bv  = (const float*)d_in[24];
  const float* t_wo  = (const float*)d_in[25];
  const float* t_bo  = (const float*)d_in[26];
  const float* mn_g  = (const float*)d_in[27];
  const float* mn_b  = (const float*)d_in[28];
  const float* mw1   = (const float*)d_in[29];
  const float* mb1   = (const float*)d_in[30];
  const float* mw2   = (const float*)d_in[31];
  const float* mb2   = (const float*)d_in[32];
  const float* fn_g  = (const float*)d_in[33];
  const float* fn_b  = (const float*)d_in[34];

  float* ws = (float*)d_ws;
  const size_t NX = 4456448;               // B*T1*HW*D
  float* X   = ws;                         // fp32 [RT][512]
  bf16*  XNb = (bf16*)(X + NX);            // bf16 [RT][512]
  bf16*  Qb  = (bf16*)((float*)XNb + NX/2);
  bf16*  Kb  = (bf16*)((float*)Qb  + NX/2);
  bf16*  Vb  = (bf16*)((float*)Kb  + NX/2);
  bf16*  Wt  = (bf16*)((float*)Vb  + NX/2); // 6 layers x 3,145,728 bf16
  bf16*  HIDb= Qb;                          // [8704][1024] bf16, aliases Qb+Kb

  float* out0 = (float*)d_out;
  float* out1 = out0 + NX;
  float* out2 = out1 + 1183744;
  float* out3 = out2 + 25165824;

  const int RS = B__*T_*HWL;           // 8192
  const int RT = B__*T1_*HWL;          // 8704
  dim3 gQs(12, 64);
  dim3 gQt(12, 68);
  dim3 g64s(8, 128);                   // 64^2-tile grids: N=512
  dim3 g64t(8, 136);
  dim3 gM1(8, 68);
  dim3 wcg(32, 32, 60);

  embed_ln_kernel<<<RT/4, 256, 0, stream>>>(codes, emb, cls, hpos, wpos, eng, enb, X);
  wconv_kernel<<<wcg,256,0,stream>>>(s_wq, s_wk, s_wv, s_wo, t_wq, t_wk, t_wv, t_wo, mw1, mw2, Wt);

  for(int i=0;i<6;i++){
    bf16* Wl = Wt + (size_t)i*3145728;
    // ---- spatial windowed attention ----
    ln_bf_kernel<<<RS/4,256,0,stream>>>(X, XNb, sn_g+i*D_, sn_b+i*D_, T_*HWL, T1_*HWL);
    gemm_qkv<<<gQs,256,0,stream>>>(XNb, Wl, s_bq+i*D_, s_bk+i*D_, s_bv+i*D_, Qb, Kb, Vb);
    spatial_attn_kernel<<<RS,256,0,stream>>>(Qb, Kb, Vb, XNb);
    gemm_mfma64<0,true,false><<<g64s,256,0,stream>>>(XNb, Wl+3*262144, s_bo+i*D_, X, X, 512, 512, T_*HWL, T1_*HWL);
    // ---- temporal RoPE causal attention (fused) ----
    ln_bf_kernel<<<RT/4,256,0,stream>>>(X, XNb, tn_g+i*D_, tn_b+i*D_, T1_*HWL, T1_*HWL);
    gemm_qkv<<<gQt,256,0,stream>>>(XNb, Wl+4*262144, t_bq+i*D_, t_bk+i*D_, t_bv+i*D_, Qb, Kb, Vb);
    fused_tattn<<<512,512,0,stream>>>(Qb, Kb, Vb, XNb,
                                      out2+(size_t)i*4194304, out3+(size_t)i*4194304,
                                      out1, (i==5)?1:0);
    gemm_mfma64<0,true,false><<<g64t,256,0,stream>>>(XNb, Wl+7*262144, t_bo+i*D_, X, X, 512, 512, RT, RT);
    avg_frame0_kernel<<<1024,256,0,stream>>>(X);
    // ---- MLP ----
    ln_bf_kernel<<<RT/4,256,0,stream>>>(X, XNb, mn_g+i*D_, mn_b+i*D_, T1_*HWL, T1_*HWL);
    gemm_mfma<1,false,true ><<<gM1,256,0,stream>>>(XNb, Wl+2097152, mb1+i*1024, HIDb, nullptr, 512, 1024, RT, RT);
    gemm_mfma64<0,true,false><<<g64t,256,0,stream>>>(HIDb, Wl+2621440, mb2+i*D_, X, X, 1024, 512, RT, RT);
  }
  ln_kernel<<<RT/4,256,0,stream>>>(X, out0, fn_g, fn_b, T1_*HWL, T1_*HWL);
}

// Round 6
// 1362.171 us; speedup vs baseline: 4.5979x; 1.0324x over previous
//
#include <hip/hip_runtime.h>
#include <hip/hip_bf16.h>
#include <math.h>

#define D_    512
#define NHH   8
#define DH_   64
#define T_    16
#define T1_   17
#define HWL   256
#define B__   2
#define NEGV  -1e9f

typedef __attribute__((ext_vector_type(8))) short short8;
typedef __attribute__((ext_vector_type(4))) short short4v;
typedef __attribute__((ext_vector_type(4))) float f32x4;
typedef __hip_bfloat16 bf16;

__device__ inline float wave_sum(float v){
  #pragma unroll
  for(int o=32;o>0;o>>=1) v += __shfl_xor(v,o,64);
  return v;
}
__device__ inline float b2f(unsigned short s){
  unsigned u = ((unsigned)s)<<16; float f; __builtin_memcpy(&f,&u,4); return f;
}
__device__ inline short f2bs(float f){
  bf16 h = __float2bfloat16(f); short s; __builtin_memcpy(&s,&h,2); return s;
}
__device__ inline void gload_lds16(const void* g, void* l){
  __builtin_amdgcn_global_load_lds((const __attribute__((address_space(1))) void*)g,
                                   (__attribute__((address_space(3))) void*)l, 16, 0, 0);
}

// ---------------- embedding + LN ----------------
__global__ __launch_bounds__(256) void embed_ln_kernel(
    const int* __restrict__ codes, const float* __restrict__ emb,
    const float* __restrict__ cls, const float* __restrict__ hpos,
    const float* __restrict__ wpos, const float* __restrict__ g,
    const float* __restrict__ bta, float* __restrict__ X){
  int row  = blockIdx.x*4 + (threadIdx.x>>6);
  int lane = threadIdx.x & 63;
  int hw = row % HWL; int bt = row / HWL; int t = bt % T1_; int bb = bt / T1_;
  float v[8];
  if(t < T_){
    int code = codes[(bb*T_ + t)*HWL + hw];
    const float* ep = emb  + (size_t)code*D_;
    const float* hp = hpos + (size_t)(hw & 15)*D_;
    const float* wp = wpos + (size_t)(hw >> 4)*D_;
    #pragma unroll
    for(int j=0;j<8;j++){ int d = lane + j*64; v[j] = ep[d] + hp[d] + wp[d]; }
  } else {
    #pragma unroll
    for(int j=0;j<8;j++) v[j] = cls[lane + j*64];
  }
  float s=0;
  #pragma unroll
  for(int j=0;j<8;j++) s += v[j];
  s = wave_sum(s);
  float mean = s*(1.f/512.f);
  float s2=0;
  #pragma unroll
  for(int j=0;j<8;j++){ float d0=v[j]-mean; s2 += d0*d0; }
  s2 = wave_sum(s2);
  float inv = rsqrtf(s2*(1.f/512.f) + 1e-5f);
  float* o = X + (size_t)row*D_;
  #pragma unroll
  for(int j=0;j<8;j++){ int d = lane + j*64; o[d] = (v[j]-mean)*inv*g[d] + bta[d]; }
}

// ---------------- LayerNorm, fp32 out (final), float4 vectorized ----------------
__global__ __launch_bounds__(256) void ln_kernel(
    const float* __restrict__ in, float* __restrict__ out,
    const float* __restrict__ g, const float* __restrict__ bta,
    int c_rpb, int s_rpb){
  int row  = blockIdx.x*4 + (threadIdx.x>>6);
  int lane = threadIdx.x & 63;
  int bb = row / c_rpb; int rem = row - bb*c_rpb;
  const float4* p = (const float4*)(in + ((size_t)bb*s_rpb + rem)*D_);
  float4 a = p[lane], c = p[lane+64];
  float s = a.x+a.y+a.z+a.w + c.x+c.y+c.z+c.w;
  s = wave_sum(s);
  float mean = s*(1.f/512.f);
  float s2 = (a.x-mean)*(a.x-mean)+(a.y-mean)*(a.y-mean)+(a.z-mean)*(a.z-mean)+(a.w-mean)*(a.w-mean)
           + (c.x-mean)*(c.x-mean)+(c.y-mean)*(c.y-mean)+(c.z-mean)*(c.z-mean)+(c.w-mean)*(c.w-mean);
  s2 = wave_sum(s2);
  float inv = rsqrtf(s2*(1.f/512.f) + 1e-5f);
  const float4* g4 = (const float4*)g; const float4* b4 = (const float4*)bta;
  float4 gv=g4[lane], gw=g4[lane+64], bv=b4[lane], bw=b4[lane+64];
  float4 o0 = { (a.x-mean)*inv*gv.x+bv.x, (a.y-mean)*inv*gv.y+bv.y,
                (a.z-mean)*inv*gv.z+bv.z, (a.w-mean)*inv*gv.w+bv.w };
  float4 o1 = { (c.x-mean)*inv*gw.x+bw.x, (c.y-mean)*inv*gw.y+bw.y,
                (c.z-mean)*inv*gw.z+bw.z, (c.w-mean)*inv*gw.w+bw.w };
  float4* o = (float4*)(out + (size_t)row*D_);
  o[lane] = o0; o[lane+64] = o1;
}

// ---------------- LayerNorm, bf16 out, vectorized ----------------
__global__ __launch_bounds__(256) void ln_bf_kernel(
    const float* __restrict__ in, bf16* __restrict__ out,
    const float* __restrict__ g, const float* __restrict__ bta,
    int c_rpb, int s_rpb){
  int row  = blockIdx.x*4 + (threadIdx.x>>6);
  int lane = threadIdx.x & 63;
  int bb = row / c_rpb; int rem = row - bb*c_rpb;
  const float4* p = (const float4*)(in + ((size_t)bb*s_rpb + rem)*D_);
  float4 a = p[lane], c = p[lane+64];
  float s = a.x+a.y+a.z+a.w + c.x+c.y+c.z+c.w;
  s = wave_sum(s);
  float mean = s*(1.f/512.f);
  float s2 = (a.x-mean)*(a.x-mean)+(a.y-mean)*(a.y-mean)+(a.z-mean)*(a.z-mean)+(a.w-mean)*(a.w-mean)
           + (c.x-mean)*(c.x-mean)+(c.y-mean)*(c.y-mean)+(c.z-mean)*(c.z-mean)+(c.w-mean)*(c.w-mean);
  s2 = wave_sum(s2);
  float inv = rsqrtf(s2*(1.f/512.f) + 1e-5f);
  const float4* g4 = (const float4*)g; const float4* b4 = (const float4*)bta;
  float4 gv=g4[lane], gw=g4[lane+64], bv=b4[lane], bw=b4[lane+64];
  short4v r0 = { f2bs((a.x-mean)*inv*gv.x+bv.x), f2bs((a.y-mean)*inv*gv.y+bv.y),
                 f2bs((a.z-mean)*inv*gv.z+bv.z), f2bs((a.w-mean)*inv*gv.w+bv.w) };
  short4v r1 = { f2bs((c.x-mean)*inv*gw.x+bw.x), f2bs((c.y-mean)*inv*gw.y+bw.y),
                 f2bs((c.z-mean)*inv*gw.z+bw.z), f2bs((c.w-mean)*inv*gw.w+bw.w) };
  bf16* o = out + (size_t)row*D_;
  *(short4v*)&o[lane*4]       = r0;
  *(short4v*)&o[256 + lane*4] = r1;
}

// ---------------- weight fp32[K][N] -> bf16[N][K], ALL layers at once ----------------
__global__ __launch_bounds__(256) void wconv_kernel(
    const float* sq, const float* sk, const float* sv, const float* so,
    const float* tq, const float* tk, const float* tv, const float* to,
    const float* w1, const float* w2, bf16* __restrict__ dst){
  __shared__ float sm[32][33];
  int z = blockIdx.z; int i = z/10, id = z - i*10;
  const size_t wo = (size_t)i*262144, mo = (size_t)i*524288;
  bf16* db = dst + (size_t)i*3145728;
  const float* src; bf16* d; int K, N;
  switch(id){
    case 0: src=sq+wo; d=db+0*262144;  K=512;  N=512;  break;
    case 1: src=sk+wo; d=db+1*262144;  K=512;  N=512;  break;
    case 2: src=sv+wo; d=db+2*262144;  K=512;  N=512;  break;
    case 3: src=so+wo; d=db+3*262144;  K=512;  N=512;  break;
    case 4: src=tq+wo; d=db+4*262144;  K=512;  N=512;  break;
    case 5: src=tk+wo; d=db+5*262144;  K=512;  N=512;  break;
    case 6: src=tv+wo; d=db+6*262144;  K=512;  N=512;  break;
    case 7: src=to+wo; d=db+7*262144;  K=512;  N=512;  break;
    case 8: src=w1+mo; d=db+2097152;   K=512;  N=1024; break;
    default:src=w2+mo; d=db+2621440;   K=1024; N=512;  break;
  }
  int n0 = blockIdx.x<<5, k0 = blockIdx.y<<5;
  if(n0 >= N || k0 >= K) return;
  int tx = threadIdx.x & 31, ty = threadIdx.x >> 5;
  #pragma unroll
  for(int j=0;j<4;j++) sm[ty+j*8][tx] = src[(size_t)(k0+ty+j*8)*N + n0+tx];
  __syncthreads();
  #pragma unroll
  for(int j=0;j<4;j++) d[(size_t)(n0+ty+j*8)*K + k0+tx] = __float2bfloat16(sm[tx][ty+j*8]);
}

// ---------------- bf16 MFMA GEMM, 128x128 tile, BK=64, swizzled LDS ----------------
// LDS layout: [row][slot] with slot = logical_k16slot ^ (row&7); staged via
// pre-permuted GLOBAL source (gload_lds dest stays linear), read with same XOR.
template<int ACT, bool RES, bool OBF>
__global__ __launch_bounds__(256) void gemm_mfma(
    const bf16* __restrict__ A, const bf16* __restrict__ Wt,
    const float* __restrict__ bias, void* __restrict__ outp,
    const float* __restrict__ resid, int K, int N, int c_rpb, int o_rpb){
  __shared__ __align__(16) bf16 As[128*64];
  __shared__ __align__(16) bf16 Bs[128*64];
  const int tid  = threadIdx.x;
  const int lane = tid & 63;
  const int w    = tid >> 6;
  const int row0 = blockIdx.y << 7;
  const int col0 = blockIdx.x << 7;
  const int mb = (w>>1)*64, nb = (w&1)*64;
  size_t ga[4], gb[4];
  #pragma unroll
  for(int r=0;r<4;r++){
    int c = (r*4+w)*64 + lane;          // chunk id 0..1023
    int rw = c>>3;                      // tile row
    int ks = (c&7) ^ (rw&7);            // inverse-swizzled k-slot (involution)
    ga[r] = (size_t)(row0+rw)*K + (ks<<3);
    gb[r] = (size_t)(col0+rw)*K + (ks<<3);
  }
  f32x4 acc[4][4] = {};
  for(int k0=0;k0<K;k0+=64){
    #pragma unroll
    for(int r=0;r<4;r++){
      gload_lds16(A  + ga[r] + k0, As + (size_t)(r*4+w)*512);
      gload_lds16(Wt + gb[r] + k0, Bs + (size_t)(r*4+w)*512);
    }
    __syncthreads();
    const short8* Av = (const short8*)As;
    const short8* Bv = (const short8*)Bs;
    #pragma unroll
    for(int kk=0;kk<2;kk++){
      const int slot = (lane>>4) + kk*4;
      short8 af[4], bfr[4];
      #pragma unroll
      for(int mi=0;mi<4;mi++){ int rw = mb + mi*16 + (lane&15); af[mi]  = Av[rw*8 + (slot ^ (rw&7))]; }
      #pragma unroll
      for(int ni=0;ni<4;ni++){ int rw = nb + ni*16 + (lane&15); bfr[ni] = Bv[rw*8 + (slot ^ (rw&7))]; }
      #pragma unroll
      for(int mi=0;mi<4;mi++)
        #pragma unroll
        for(int ni=0;ni<4;ni++)
          acc[mi][ni] = __builtin_amdgcn_mfma_f32_16x16x32_bf16(af[mi], bfr[ni], acc[mi][ni], 0,0,0);
    }
    __syncthreads();
  }
  #pragma unroll
  for(int mi=0;mi<4;mi++){
    #pragma unroll
    for(int r=0;r<4;r++){
      int row = row0 + mb + mi*16 + (lane>>4)*4 + r;
      int bb = row / c_rpb;
      size_t orow = (size_t)bb*o_rpb + (row - bb*c_rpb);
      #pragma unroll
      for(int ni=0;ni<4;ni++){
        int col = col0 + nb + ni*16 + (lane&15);
        float v = acc[mi][ni][r] + bias[col];
        if(ACT==1) v = tanhf(v);
        if(RES) v += resid[orow*(size_t)N + col];
        if(OBF) ((bf16*)outp)[orow*(size_t)N + col] = __float2bfloat16(v);
        else    ((float*)outp)[orow*(size_t)N + col] = v;
      }
    }
  }
}

// ---------------- bf16 MFMA GEMM, 64x64 tile, BK=64, swizzled ----------------
template<int ACT, bool RES, bool OBF>
__global__ __launch_bounds__(256) void gemm_mfma64(
    const bf16* __restrict__ A, const bf16* __restrict__ Wt,
    const float* __restrict__ bias, void* __restrict__ outp,
    const float* __restrict__ resid, int K, int N, int c_rpb, int o_rpb){
  __shared__ __align__(16) bf16 As[64*64];
  __shared__ __align__(16) bf16 Bs[64*64];
  const int tid  = threadIdx.x;
  const int lane = tid & 63;
  const int w    = tid >> 6;
  const int row0 = blockIdx.y << 6;
  const int col0 = blockIdx.x << 6;
  const int mw = (w>>1)*32, nw = (w&1)*32;
  size_t ga[2], gb[2];
  #pragma unroll
  for(int r=0;r<2;r++){
    int c = (r*4+w)*64 + lane;          // chunk id 0..511
    int rw = c>>3;
    int ks = (c&7) ^ (rw&7);
    ga[r] = (size_t)(row0+rw)*K + (ks<<3);
    gb[r] = (size_t)(col0+rw)*K + (ks<<3);
  }
  f32x4 acc[2][2] = {};
  for(int k0=0;k0<K;k0+=64){
    #pragma unroll
    for(int r=0;r<2;r++){
      gload_lds16(A  + ga[r] + k0, As + (size_t)(r*4+w)*512);
      gload_lds16(Wt + gb[r] + k0, Bs + (size_t)(r*4+w)*512);
    }
    __syncthreads();
    const short8* Av = (const short8*)As;
    const short8* Bv = (const short8*)Bs;
    #pragma unroll
    for(int kk=0;kk<2;kk++){
      const int slot = (lane>>4) + kk*4;
      short8 af[2], bfr[2];
      #pragma unroll
      for(int mi=0;mi<2;mi++){ int rw = mw + mi*16 + (lane&15); af[mi]  = Av[rw*8 + (slot ^ (rw&7))]; }
      #pragma unroll
      for(int ni=0;ni<2;ni++){ int rw = nw + ni*16 + (lane&15); bfr[ni] = Bv[rw*8 + (slot ^ (rw&7))]; }
      #pragma unroll
      for(int mi=0;mi<2;mi++)
        #pragma unroll
        for(int ni=0;ni<2;ni++)
          acc[mi][ni] = __builtin_amdgcn_mfma_f32_16x16x32_bf16(af[mi], bfr[ni], acc[mi][ni], 0,0,0);
    }
    __syncthreads();
  }
  #pragma unroll
  for(int mi=0;mi<2;mi++){
    #pragma unroll
    for(int r=0;r<4;r++){
      int row = row0 + mw + mi*16 + (lane>>4)*4 + r;
      int bb = row / c_rpb;
      size_t orow = (size_t)bb*o_rpb + (row - bb*c_rpb);
      #pragma unroll
      for(int ni=0;ni<2;ni++){
        int col = col0 + nw + ni*16 + (lane&15);
        float v = acc[mi][ni][r] + bias[col];
        if(ACT==1) v = tanhf(v);
        if(RES) v += resid[orow*(size_t)N + col];
        if(OBF) ((bf16*)outp)[orow*(size_t)N + col] = __float2bfloat16(v);
        else    ((float*)outp)[orow*(size_t)N + col] = v;
      }
    }
  }
}

// ---------------- fused QKV GEMM: N=1536, BK=64, swizzled, bf16 outs ----------------
__global__ __launch_bounds__(256) void gemm_qkv(
    const bf16* __restrict__ A, const bf16* __restrict__ Wt,
    const float* __restrict__ bq, const float* __restrict__ bk, const float* __restrict__ bv,
    bf16* __restrict__ Qo, bf16* __restrict__ Ko, bf16* __restrict__ Vo){
  const int K = 512;
  __shared__ __align__(16) bf16 As[128*64];
  __shared__ __align__(16) bf16 Bs[128*64];
  const int tid  = threadIdx.x;
  const int lane = tid & 63;
  const int w    = tid >> 6;
  const int row0 = blockIdx.y << 7;
  const int col0 = blockIdx.x << 7;
  const int mb = (w>>1)*64, nb = (w&1)*64;
  size_t ga[4], gb[4];
  #pragma unroll
  for(int r=0;r<4;r++){
    int c = (r*4+w)*64 + lane;
    int rw = c>>3;
    int ks = (c&7) ^ (rw&7);
    ga[r] = (size_t)(row0+rw)*K + (ks<<3);
    gb[r] = (size_t)(col0+rw)*K + (ks<<3);
  }
  f32x4 acc[4][4] = {};
  for(int k0=0;k0<K;k0+=64){
    #pragma unroll
    for(int r=0;r<4;r++){
      gload_lds16(A  + ga[r] + k0, As + (size_t)(r*4+w)*512);
      gload_lds16(Wt + gb[r] + k0, Bs + (size_t)(r*4+w)*512);
    }
    __syncthreads();
    const short8* Av = (const short8*)As;
    const short8* Bv = (const short8*)Bs;
    #pragma unroll
    for(int kk=0;kk<2;kk++){
      const int slot = (lane>>4) + kk*4;
      short8 af[4], bfr[4];
      #pragma unroll
      for(int mi=0;mi<4;mi++){ int rw = mb + mi*16 + (lane&15); af[mi]  = Av[rw*8 + (slot ^ (rw&7))]; }
      #pragma unroll
      for(int ni=0;ni<4;ni++){ int rw = nb + ni*16 + (lane&15); bfr[ni] = Bv[rw*8 + (slot ^ (rw&7))]; }
      #pragma unroll
      for(int mi=0;mi<4;mi++)
        #pragma unroll
        for(int ni=0;ni<4;ni++)
          acc[mi][ni] = __builtin_amdgcn_mfma_f32_16x16x32_bf16(af[mi], bfr[ni], acc[mi][ni], 0,0,0);
    }
    __syncthreads();
  }
  const int sel = col0 >> 9;
  bf16* outp = (sel==0) ? Qo : (sel==1 ? Ko : Vo);
  const float* bp = (sel==0) ? bq : (sel==1 ? bk : bv);
  const int cb = col0 & 511;
  #pragma unroll
  for(int mi=0;mi<4;mi++){
    #pragma unroll
    for(int r=0;r<4;r++){
      int row = row0 + mb + mi*16 + (lane>>4)*4 + r;
      #pragma unroll
      for(int ni=0;ni<4;ni++){
        int col = cb + nb + ni*16 + (lane&15);
        outp[(size_t)row*512 + col] = __float2bfloat16(acc[mi][ni][r] + bp[col]);
      }
    }
  }
}

// ---------------- spatial 3x3 windowed attention: paired bf16, 2 heads/wave ----------------
__global__ __launch_bounds__(256) void spatial_attn_kernel(
    const bf16* __restrict__ Q, const bf16* __restrict__ K,
    const bf16* __restrict__ V, bf16* __restrict__ O){
  int loc = blockIdx.x;
  int hw = loc & 255;
  int hh = hw >> 4, ww = hw & 15;
  int tid = threadIdx.x, lane = tid & 63, w = tid >> 6;
  int h = w*2 + (lane>>5);
  int j = lane & 31;
  size_t base = (size_t)loc*D_ + h*DH_ + 2*j;
  unsigned uq = *(const unsigned*)&Q[base];
  float q0 = b2f((unsigned short)uq), q1 = b2f((unsigned short)(uq>>16));
  float lg[9]; int nrow[9];
  #pragma unroll
  for(int s=0;s<9;s++){
    int a = s/3 - 1, b2_ = s%3 - 1;
    int nh = hh + a, nw = ww + b2_;
    bool ok = ((unsigned)nh < 16u) && ((unsigned)nw < 16u);
    nrow[s] = ok ? (loc - hw + (nh<<4) + nw) : -1;
    float p = 0.f;
    if(ok){
      unsigned uk = *(const unsigned*)&K[(size_t)nrow[s]*D_ + h*DH_ + 2*j];
      p = q0*b2f((unsigned short)uk) + q1*b2f((unsigned short)(uk>>16));
    }
    #pragma unroll
    for(int o=16;o>0;o>>=1) p += __shfl_xor(p, o, 64);
    lg[s] = ok ? p*0.125f : NEGV;
  }
  float m = lg[0];
  #pragma unroll
  for(int s=1;s<9;s++) m = fmaxf(m, lg[s]);
  float den = 0.f, wv[9];
  #pragma unroll
  for(int s=0;s<9;s++){ wv[s] = __expf(lg[s]-m); den += wv[s]; }
  float inv = 1.f/den;
  float a0 = 0.f, a1 = 0.f;
  #pragma unroll
  for(int s=0;s<9;s++){
    if(nrow[s] >= 0){
      unsigned uv = *(const unsigned*)&V[(size_t)nrow[s]*D_ + h*DH_ + 2*j];
      a0 += wv[s]*b2f((unsigned short)uv);
      a1 += wv[s]*b2f((unsigned short)(uv>>16));
    }
  }
  unsigned up = (unsigned)(unsigned short)f2bs(a0*inv) | ((unsigned)(unsigned short)f2bs(a1*inv) << 16);
  *(unsigned*)&O[base] = up;
}

// ---------------- fused temporal attention: block = (b,hw), 8 waves = 8 heads ----------------
__global__ __launch_bounds__(512) void fused_tattn(
    const bf16* __restrict__ Qb, const bf16* __restrict__ Kb, const bf16* __restrict__ Vb,
    bf16* __restrict__ O, float* __restrict__ kout, float* __restrict__ vout,
    float* __restrict__ ltout, int write_lt){
  __shared__ __align__(16) bf16 Qs[17*520];
  __shared__ __align__(16) bf16 Ks[17*520];
  __shared__ __align__(16) bf16 Vs[17*512];
  __shared__ float Ws[8][17][18];
  const int tid = threadIdx.x, w = tid>>6, lane = tid&63;
  const int hw = blockIdx.x & 255, b = blockIdx.x >> 8;
  const size_t tstr = (size_t)HWL*D_;
  const size_t rb0 = ((size_t)(b*T1_)*HWL + hw)*D_;
  for(int t=w; t<17; t+=8){
    size_t src = rb0 + (size_t)t*tstr + lane*8;
    *(short8*)&Qs[t*520 + lane*8] = *(const short8*)&Qb[src];
    *(short8*)&Ks[t*520 + lane*8] = *(const short8*)&Kb[src];
    *(short8*)&Vs[t*512 + lane*8] = *(const short8*)&Vb[src];
  }
  __syncthreads();
  {
    int i = lane & 31;
    float freq = __expf(-9.210340372f * (float)i * (1.f/32.f));
    bf16* P = (lane < 32) ? Qs : Ks;
    #pragma unroll
    for(int t=0;t<17;t++){
      float sn, cs; __sincosf((float)t*freq, &sn, &cs);
      int idx = t*520 + w*64 + i;
      float x1 = __bfloat162float(P[idx]);
      float x2 = __bfloat162float(P[idx+32]);
      P[idx]    = __float2bfloat16(x1*cs - x2*sn);
      P[idx+32] = __float2bfloat16(x2*cs + x1*sn);
    }
  }
  __syncthreads();
  {
    size_t eb = (((size_t)(b*HWL + hw)*NHH + w)*16)*64 + lane;
    #pragma unroll
    for(int t=0;t<16;t++){
      kout[eb + t*64] = __bfloat162float(Ks[t*520 + w*64 + lane]);
      vout[eb + t*64] = __bfloat162float(Vs[t*512 + w*64 + lane]);
    }
  }
  size_t lb = ((size_t)(b*HWL + hw)*NHH + w)*289;
  for(int p=lane; p<289; p+=64){
    int t = p/17, u = p - t*17;
    float d = 0.f;
    #pragma unroll
    for(int jj=0;jj<8;jj++){
      short8 qq = *(short8*)&Qs[t*520 + w*64 + jj*8];
      short8 kk = *(short8*)&Ks[u*520 + w*64 + jj*8];
      #pragma unroll
      for(int e=0;e<8;e++) d += b2f((unsigned short)qq[e]) * b2f((unsigned short)kk[e]);
    }
    bool masked = (u > t) || (t == 16 && u == 16);
    float lg = masked ? NEGV : d*0.125f;
    Ws[w][t][u] = lg;
    if(write_lt) ltout[lb + t*17 + u] = lg;
  }
  __syncthreads();
  if(lane < 17){
    float m = -1e30f;
    #pragma unroll
    for(int u=0;u<17;u++) m = fmaxf(m, Ws[w][lane][u]);
    float den = 0.f, e[17];
    #pragma unroll
    for(int u=0;u<17;u++){ e[u] = __expf(Ws[w][lane][u]-m); den += e[u]; }
    float inv = 1.f/den;
    #pragma unroll
    for(int u=0;u<17;u++) Ws[w][lane][u] = e[u]*inv;
  }
  __syncthreads();
  float Vr[17];
  #pragma unroll
  for(int u=0;u<17;u++) Vr[u] = __bfloat162float(Vs[u*512 + w*64 + lane]);
  #pragma unroll
  for(int t=0;t<17;t++){
    float acc = 0.f;
    #pragma unroll
    for(int u=0;u<17;u++) acc += Ws[w][t][u]*Vr[u];
    O[rb0 + (size_t)t*tstr + w*64 + lane] = __float2bfloat16(acc);
  }
}

// ---------------- frame-0 spatial mean broadcast ----------------
__global__ __launch_bounds__(256) void avg_frame0_kernel(float* __restrict__ X){
  int d = blockIdx.x & 511; int bb = blockIdx.x >> 9;
  int hw = threadIdx.x;
  __shared__ float sm[256];
  size_t idx = ((size_t)(bb*T1_)*HWL + hw)*D_ + d;
  sm[hw] = X[idx];
  __syncthreads();
  for(int o=128;o>0;o>>=1){ if(hw<o) sm[hw] += sm[hw+o]; __syncthreads(); }
  X[idx] = sm[0]*(1.f/256.f);
}

extern "C" void kernel_launch(void* const* d_in, const int* in_sizes, int n_in,
                              void* d_out, int out_size, void* d_ws, size_t ws_size,
                              hipStream_t stream){
  const int*   codes = (const int*)  d_in[0];
  const float* emb   = (const float*)d_in[1];
  const float* cls   = (const float*)d_in[2];
  const float* hpos  = (const float*)d_in[3];
  const float* wpos  = (const float*)d_in[4];
  const float* eng   = (const float*)d_in[5];
  const float* enb   = (const float*)d_in[6];
  const float* sn_g  = (const float*)d_in[7];
  const float* sn_b  = (const float*)d_in[8];
  const float* s_wq  = (const float*)d_in[9];
  const float* s_bq  = (const float*)d_in[10];
  const float* s_wk  = (const float*)d_in[11];
  const float* s_bk  = (const float*)d_in[12];
  const float* s_wv  = (const float*)d_in[13];
  const float* s_bv  = (const float*)d_in[14];
  const float* s_wo  = (const float*)d_in[15];
  const float* s_bo  = (const float*)d_in[16];
  const float* tn_g  = (const float*)d_in[17];
  const float* tn_b  = (const float*)d_in[18];
  const float* t_wq  = (const float*)d_in[19];
  const float* t_bq  = (const float*)d_in[20];
  const float* t_wk  = (const float*)d_in[21];
  const float* t_bk  = (const float*)d_in[22];
  const float* t_wv  = (const float*)d_in[23];
  const float* t_bv  = (const float*)d_in[24];
  const float* t_wo  = (const float*)d_in[25];
  const float* t_bo  = (const float*)d_in[26];
  const float* mn_g  = (const float*)d_in[27];
  const float* mn_b  = (const float*)d_in[28];
  const float* mw1   = (const float*)d_in[29];
  const float* mb1   = (const float*)d_in[30];
  const float* mw2   = (const float*)d_in[31];
  const float* mb2   = (const float*)d_in[32];
  const float* fn_g  = (const float*)d_in[33];
  const float* fn_b  = (const float*)d_in[34];

  float* ws = (float*)d_ws;
  const size_t NX = 4456448;               // B*T1*HW*D
  float* X   = ws;                         // fp32 [RT][512]
  bf16*  XNb = (bf16*)(X + NX);            // bf16 [RT][512]
  bf16*  Qb  = (bf16*)((float*)XNb + NX/2);
  bf16*  Kb  = (bf16*)((float*)Qb  + NX/2);
  bf16*  Vb  = (bf16*)((float*)Kb  + NX/2);
  bf16*  Wt  = (bf16*)((float*)Vb  + NX/2); // 6 layers x 3,145,728 bf16
  bf16*  HIDb= Qb;                          // [8704][1024] bf16, aliases Qb+Kb

  float* out0 = (float*)d_out;
  float* out1 = out0 + NX;
  float* out2 = out1 + 1183744;
  float* out3 = out2 + 25165824;

  const int RS = B__*T_*HWL;           // 8192
  const int RT = B__*T1_*HWL;          // 8704
  dim3 gQs(12, 64);
  dim3 gQt(12, 68);
  dim3 g64s(8, 128);                   // 64^2-tile grids: N=512
  dim3 g64t(8, 136);
  dim3 gM1(8, 68);
  dim3 wcg(32, 32, 60);

  embed_ln_kernel<<<RT/4, 256, 0, stream>>>(codes, emb, cls, hpos, wpos, eng, enb, X);
  wconv_kernel<<<wcg,256,0,stream>>>(s_wq, s_wk, s_wv, s_wo, t_wq, t_wk, t_wv, t_wo, mw1, mw2, Wt);

  for(int i=0;i<6;i++){
    bf16* Wl = Wt + (size_t)i*3145728;
    // ---- spatial windowed attention ----
    ln_bf_kernel<<<RS/4,256,0,stream>>>(X, XNb, sn_g+i*D_, sn_b+i*D_, T_*HWL, T1_*HWL);
    gemm_qkv<<<gQs,256,0,stream>>>(XNb, Wl, s_bq+i*D_, s_bk+i*D_, s_bv+i*D_, Qb, Kb, Vb);
    spatial_attn_kernel<<<RS,256,0,stream>>>(Qb, Kb, Vb, XNb);
    gemm_mfma64<0,true,false><<<g64s,256,0,stream>>>(XNb, Wl+3*262144, s_bo+i*D_, X, X, 512, 512, T_*HWL, T1_*HWL);
    // ---- temporal RoPE causal attention (fused) ----
    ln_bf_kernel<<<RT/4,256,0,stream>>>(X, XNb, tn_g+i*D_, tn_b+i*D_, T1_*HWL, T1_*HWL);
    gemm_qkv<<<gQt,256,0,stream>>>(XNb, Wl+4*262144, t_bq+i*D_, t_bk+i*D_, t_bv+i*D_, Qb, Kb, Vb);
    fused_tattn<<<512,512,0,stream>>>(Qb, Kb, Vb, XNb,
                                      out2+(size_t)i*4194304, out3+(size_t)i*4194304,
                                      out1, (i==5)?1:0);
    gemm_mfma64<0,true,false><<<g64t,256,0,stream>>>(XNb, Wl+7*262144, t_bo+i*D_, X, X, 512, 512, RT, RT);
    avg_frame0_kernel<<<1024,256,0,stream>>>(X);
    // ---- MLP ----
    ln_bf_kernel<<<RT/4,256,0,stream>>>(X, XNb, mn_g+i*D_, mn_b+i*D_, T1_*HWL, T1_*HWL);
    gemm_mfma<1,false,true ><<<gM1,256,0,stream>>>(XNb, Wl+2097152, mb1+i*1024, HIDb, nullptr, 512, 1024, RT, RT);
    gemm_mfma64<0,true,false><<<g64t,256,0,stream>>>(HIDb, Wl+2621440, mb2+i*D_, X, X, 1024, 512, RT, RT);
  }
  ln_kernel<<<RT/4,256,0,stream>>>(X, out0, fn_g, fn_b, T1_*HWL, T1_*HWL);
}